// Round 5
// baseline (2006.923 us; speedup 1.0000x reference)
//
#include <hip/hip_runtime.h>

#define NC_N 100000
#define NV_N 100000
#define E_N  3200000
#define NKEY 200000          // unified key space: [0,NC) cons, [NC,NC+NV) vars
#define NBKT 1563            // ceil(200000/128) coarse buckets of 128 keys
#define BCAP 7168            // per-bucket LDS capacity (mean 4094, sigma ~64)

typedef __attribute__((ext_vector_type(8))) __bf16 bf16x8;
typedef __attribute__((ext_vector_type(4))) float  f32x4;

// ---------------- node embedding kernels ----------------

__global__ __launch_bounds__(256) void k_embed_cons(
    const float* __restrict__ f, const float* __restrict__ W,
    const float* __restrict__ b, float* __restrict__ out)
{
    int n = blockIdx.x * blockDim.x + threadIdx.x;
    if (n >= NC_N) return;
    float f0 = f[2*(size_t)n], f1 = f[2*(size_t)n + 1];
    float4* dst = (float4*)(out + (size_t)n * 32);
    #pragma unroll
    for (int q = 0; q < 8; q++){
        float4 r;
        #pragma unroll
        for (int j = 0; j < 4; j++){
            int o = q*4 + j;
            (&r.x)[j] = fmaxf(fmaf(f0, W[o], fmaf(f1, W[32 + o], b[o])), 0.f);
        }
        dst[q] = r;
    }
}

__global__ __launch_bounds__(256) void k_embed_vars(
    const float* __restrict__ f, const float* __restrict__ W,
    const float* __restrict__ b, float* __restrict__ out)
{
    int n = blockIdx.x * blockDim.x + threadIdx.x;
    if (n >= NV_N) return;
    float x[9];
    #pragma unroll
    for (int k = 0; k < 9; k++) x[k] = f[9*(size_t)n + k];
    float4* dst = (float4*)(out + (size_t)n * 32);
    #pragma unroll
    for (int q = 0; q < 8; q++){
        float4 r;
        #pragma unroll
        for (int j = 0; j < 4; j++){
            int o = q*4 + j;
            float s = b[o];
            #pragma unroll
            for (int k = 0; k < 9; k++) s = fmaf(x[k], W[k*32 + o], s);
            (&r.x)[j] = fmaxf(s, 0.f);
        }
        dst[q] = r;
    }
}

// out[N,32] = x[N,32] @ W[32,32] (+ bias, optional). No relu.
__global__ __launch_bounds__(256) void k_mm32(
    const float* __restrict__ x, const float* __restrict__ W,
    const float* __restrict__ bias, float* __restrict__ out, int n)
{
    int i = blockIdx.x * blockDim.x + threadIdx.x;
    if (i >= n) return;
    float h[32];
    if (bias){
        #pragma unroll
        for (int o = 0; o < 32; o++) h[o] = bias[o];
    } else {
        #pragma unroll
        for (int o = 0; o < 32; o++) h[o] = 0.f;
    }
    const float4* xp = (const float4*)(x + (size_t)i * 32);
    #pragma unroll
    for (int q = 0; q < 8; q++){
        float4 t = xp[q];
        #pragma unroll
        for (int j = 0; j < 4; j++){
            float xk = (&t.x)[j];
            const float* w = W + (q*4 + j)*32;
            #pragma unroll
            for (int o = 0; o < 32; o++) h[o] = fmaf(xk, w[o], h[o]);
        }
    }
    float4* dst = (float4*)(out + (size_t)i * 32);
    #pragma unroll
    for (int q = 0; q < 8; q++){
        float4 r;
        #pragma unroll
        for (int j = 0; j < 4; j++) (&r.x)[j] = h[q*4 + j];
        dst[q] = r;
    }
}

__global__ __launch_bounds__(256) void k_badd(
    float* __restrict__ P, const float* __restrict__ b, int n)
{
    int i = blockIdx.x * blockDim.x + threadIdx.x;
    if (i >= n * 32) return;
    P[i] += b[i & 31];
}

// ---------------- two-level bucketed CSR build ----------------

// coarse histogram: 1563 buckets of 128 keys
__global__ __launch_bounds__(256) void k_bhist(
    const int* __restrict__ eC, const int* __restrict__ eV, int* __restrict__ bcnt)
{
    int e = blockIdx.x * blockDim.x + threadIdx.x;
    if (e >= E_N) return;
    atomicAdd(&bcnt[eC[e] >> 7], 1);
    atomicAdd(&bcnt[(NC_N + eV[e]) >> 7], 1);
}

// one block: exclusive scan of 1563 bucket counts -> bbase, init bcur
__global__ __launch_bounds__(256) void k_bscan(
    const int* __restrict__ bcnt, int* __restrict__ bbase, int* __restrict__ bcur)
{
    __shared__ int part[256];
    int t = threadIdx.x;
    int lo = t * 8, hi = lo + 8;
    int s = 0;
    for (int i = lo; i < hi; i++) if (i < NBKT) s += bcnt[i];
    part[t] = s;
    __syncthreads();
    #pragma unroll
    for (int d = 1; d < 256; d <<= 1){
        int u = (t >= d) ? part[t - d] : 0;
        __syncthreads();
        part[t] += u;
        __syncthreads();
    }
    int run = part[t] - s;              // exclusive prefix of this chunk
    for (int i = lo; i < hi; i++){
        if (i < NBKT){
            int c = bcnt[i];
            bbase[i] = run;
            bcur[i]  = run;
            run += c;
        }
    }
}

// scatter packed entries (key_local<<17 | other) into coarse bucket streams
__global__ __launch_bounds__(256) void k_bucketA(
    const int* __restrict__ eC, const int* __restrict__ eV,
    int* __restrict__ bcur, unsigned* __restrict__ pbuf)
{
    int e = blockIdx.x * blockDim.x + threadIdx.x;
    if (e >= E_N) return;
    int kc = eC[e], kv = eV[e];
    // cons-keyed entry, payload = var index
    int p1 = atomicAdd(&bcur[kc >> 7], 1);
    pbuf[p1] = ((unsigned)(kc & 127) << 17) | (unsigned)kv;
    // vars-keyed entry, payload = cons index
    int gk = NC_N + kv;
    int p2 = atomicAdd(&bcur[gk >> 7], 1);
    pbuf[p2] = ((unsigned)(gk & 127) << 17) | (unsigned)kc;
}

// per bucket: LDS stage + 128-bin hist/scan -> cnt/offs, LDS permute, coalesced out
__global__ __launch_bounds__(256) void k_bucketB(
    const unsigned* __restrict__ pbuf, const int* __restrict__ bbase,
    const int* __restrict__ bcnt, int* __restrict__ cnt,
    int* __restrict__ offs, int* __restrict__ elist)
{
    __shared__ unsigned sin[BCAP];
    __shared__ int sout[BCAP];
    __shared__ int hist[128], curs[128], scn[128];
    int b = blockIdx.x;
    int base = bbase[b];
    int n = bcnt[b];
    if (n > BCAP) n = BCAP;             // safety clamp (never hit for this input)
    int t = threadIdx.x;
    if (t < 128) hist[t] = 0;
    __syncthreads();
    for (int i = t; i < n; i += 256){
        unsigned p = pbuf[base + i];
        sin[i] = p;
        atomicAdd(&hist[p >> 17], 1);
    }
    __syncthreads();
    if (t < 128) scn[t] = hist[t];
    __syncthreads();
    #pragma unroll
    for (int d = 1; d < 128; d <<= 1){
        int u = 0;
        if (t < 128 && t >= d) u = scn[t - d];
        __syncthreads();
        if (t < 128) scn[t] += u;
        __syncthreads();
    }
    if (t < 128){
        int ex = scn[t] - hist[t];      // exclusive scan
        curs[t] = ex;
        int g = b * 128 + t;
        if (g < NKEY){
            cnt[g]  = hist[t];
            offs[g] = base + ex;
        }
    }
    __syncthreads();
    for (int i = t; i < n; i += 256){
        unsigned p = sin[i];
        int pos = atomicAdd(&curs[p >> 17], 1);
        sout[pos] = (int)(p & 0x1FFFFu);
    }
    __syncthreads();
    for (int i = t; i < n; i += 256) elist[base + i] = sout[i];
}

// ---------------- W2 fragment prep (hi/lo bf16 split, MFMA B-layout) ----------
__global__ __launch_bounds__(128) void k_w2prep(
    const float* __restrict__ W2, __bf16* __restrict__ w2hi, __bf16* __restrict__ w2lo)
{
    int t = threadIdx.x;
    if (t >= 128) return;
    int h = t >> 6, l = t & 63;
    bf16x8 vh, vl;
    #pragma unroll
    for (int j = 0; j < 8; j++){
        float w = W2[((l >> 4) * 8 + j) * 32 + h * 16 + (l & 15)];
        __bf16 hi = (__bf16)w;
        vh[j] = hi;
        vl[j] = (__bf16)(w - (float)hi);
    }
    ((bf16x8*)w2hi)[t] = vh;
    ((bf16x8*)w2lo)[t] = vl;
}

// ---------------- MFMA edge pass: one wave per target node -------------------
__global__ __launch_bounds__(256) void k_edge_mfma(
    const float* __restrict__ Pconst, const float* __restrict__ Pvar,
    const int* __restrict__ offs, const int* __restrict__ cnt,
    const int* __restrict__ elist,
    const __bf16* __restrict__ w2hi, const __bf16* __restrict__ w2lo,
    const float* __restrict__ b2, float* __restrict__ accum, int n)
{
    int wid = (blockIdx.x * 256 + threadIdx.x) >> 6;
    int l   = threadIdx.x & 63;
    if (wid >= n) return;
    int row = l & 15;     // A-row (edge within tile) / C-col
    int kg  = l >> 4;     // k-chunk group

    bf16x8 wh0 = ((const bf16x8*)w2hi)[l];
    bf16x8 wh1 = ((const bf16x8*)w2hi)[64 + l];
    bf16x8 wl0 = ((const bf16x8*)w2lo)[l];
    bf16x8 wl1 = ((const bf16x8*)w2lo)[64 + l];
    float b2a = b2[row];
    float b2b = b2[16 + row];

    const float* pc = Pconst + (size_t)wid * 32 + kg * 8;
    f32x4 pc0 = *(const f32x4*)pc;
    f32x4 pc1 = *(const f32x4*)(pc + 4);

    int start = offs[wid], deg = cnt[wid];
    float acc0 = 0.f, acc1 = 0.f;
    int ntile = (deg + 15) >> 4;

    for (int t = 0; t < ntile; t++){
        int r  = t * 16 + row;
        int rc = (r < deg) ? r : (deg - 1);
        int other = elist[start + rc];
        const float* pv = Pvar + (size_t)other * 32 + kg * 8;
        f32x4 a0 = *(const f32x4*)pv;
        f32x4 a1 = *(const f32x4*)(pv + 4);

        bf16x8 ahi, alo;
        #pragma unroll
        for (int j = 0; j < 4; j++){
            float h0 = fmaxf(pc0[j] + a0[j], 0.f);
            float h1 = fmaxf(pc1[j] + a1[j], 0.f);
            __bf16 H0 = (__bf16)h0;
            __bf16 H1 = (__bf16)h1;
            ahi[j]     = H0;  alo[j]     = (__bf16)(h0 - (float)H0);
            ahi[4 + j] = H1;  alo[4 + j] = (__bf16)(h1 - (float)H1);
        }

        f32x4 c0 = {0.f, 0.f, 0.f, 0.f}, c1 = {0.f, 0.f, 0.f, 0.f};
        c0 = __builtin_amdgcn_mfma_f32_16x16x32_bf16(ahi, wh0, c0, 0, 0, 0);
        c0 = __builtin_amdgcn_mfma_f32_16x16x32_bf16(ahi, wl0, c0, 0, 0, 0);
        c0 = __builtin_amdgcn_mfma_f32_16x16x32_bf16(alo, wh0, c0, 0, 0, 0);
        c1 = __builtin_amdgcn_mfma_f32_16x16x32_bf16(ahi, wh1, c1, 0, 0, 0);
        c1 = __builtin_amdgcn_mfma_f32_16x16x32_bf16(ahi, wl1, c1, 0, 0, 0);
        c1 = __builtin_amdgcn_mfma_f32_16x16x32_bf16(alo, wh1, c1, 0, 0, 0);

        #pragma unroll
        for (int rr = 0; rr < 4; rr++){
            int er = t * 16 + kg * 4 + rr;   // C row = edge index
            if (er < deg){
                acc0 += fmaxf(c0[rr] + b2a, 0.f);
                acc1 += fmaxf(c1[rr] + b2b, 0.f);
            }
        }
    }

    acc0 += __shfl_xor(acc0, 16, 64);
    acc0 += __shfl_xor(acc0, 32, 64);
    acc1 += __shfl_xor(acc1, 16, 64);
    acc1 += __shfl_xor(acc1, 32, 64);

    if (l < 16)      accum[(size_t)wid * 32 + l] = acc0;       // cols 0..15
    else if (l < 32) accum[(size_t)wid * 32 + l] = acc1;       // cols 16..31
}

// ---------------- representation / output ----------------

__global__ __launch_bounds__(256) void k_consrep(
    const float* __restrict__ acc, float* __restrict__ cemb,
    const float* __restrict__ W, const float* __restrict__ b)
{
    int n = blockIdx.x * blockDim.x + threadIdx.x;
    if (n >= NC_N) return;
    float h[32];
    #pragma unroll
    for (int o = 0; o < 32; o++) h[o] = b[o];
    const float4* ap = (const float4*)(acc + (size_t)n * 32);
    #pragma unroll
    for (int q = 0; q < 8; q++){
        float4 t = ap[q];
        #pragma unroll
        for (int j = 0; j < 4; j++){
            float xk = (&t.x)[j];
            const float* w = W + (q*4 + j)*32;
            #pragma unroll
            for (int o = 0; o < 32; o++) h[o] = fmaf(xk, w[o], h[o]);
        }
    }
    const float4* cp = (const float4*)(cemb + (size_t)n * 32);
    #pragma unroll
    for (int q = 0; q < 8; q++){
        float4 t = cp[q];
        #pragma unroll
        for (int j = 0; j < 4; j++){
            float xk = (&t.x)[j];
            const float* w = W + (32 + q*4 + j)*32;
            #pragma unroll
            for (int o = 0; o < 32; o++) h[o] = fmaf(xk, w[o], h[o]);
        }
    }
    float4* dst = (float4*)(cemb + (size_t)n * 32);
    #pragma unroll
    for (int q = 0; q < 8; q++){
        float4 r;
        #pragma unroll
        for (int j = 0; j < 4; j++) (&r.x)[j] = fmaxf(h[q*4 + j], 0.f);
        dst[q] = r;
    }
}

__global__ __launch_bounds__(256) void k_out(
    const float* __restrict__ acc, const float* __restrict__ vemb,
    const float* __restrict__ Wvr, const float* __restrict__ bvr,
    const float* __restrict__ Wo1, const float* __restrict__ bo1,
    const float* __restrict__ Wo2, const float* __restrict__ bo2,
    const float* __restrict__ Wo3, const float* __restrict__ bo3,
    float* __restrict__ out)
{
    int n = blockIdx.x * blockDim.x + threadIdx.x;
    if (n >= NV_N) return;
    float a[32];
    #pragma unroll
    for (int o = 0; o < 32; o++) a[o] = bvr[o];
    const float4* ap = (const float4*)(acc + (size_t)n * 32);
    #pragma unroll
    for (int q = 0; q < 8; q++){
        float4 t = ap[q];
        #pragma unroll
        for (int j = 0; j < 4; j++){
            float xk = (&t.x)[j];
            const float* w = Wvr + (q*4 + j)*32;
            #pragma unroll
            for (int o = 0; o < 32; o++) a[o] = fmaf(xk, w[o], a[o]);
        }
    }
    const float4* vp = (const float4*)(vemb + (size_t)n * 32);
    #pragma unroll
    for (int q = 0; q < 8; q++){
        float4 t = vp[q];
        #pragma unroll
        for (int j = 0; j < 4; j++){
            float xk = (&t.x)[j];
            const float* w = Wvr + (32 + q*4 + j)*32;
            #pragma unroll
            for (int o = 0; o < 32; o++) a[o] = fmaf(xk, w[o], a[o]);
        }
    }
    #pragma unroll
    for (int o = 0; o < 32; o++) a[o] = fmaxf(a[o], 0.f);

    float c[32];
    #pragma unroll
    for (int o = 0; o < 32; o++) c[o] = bo1[o];
    #pragma unroll
    for (int k = 0; k < 32; k++){
        float ak = a[k];
        const float* w = Wo1 + k*32;
        #pragma unroll
        for (int o = 0; o < 32; o++) c[o] = fmaf(ak, w[o], c[o]);
    }
    #pragma unroll
    for (int o = 0; o < 32; o++) c[o] = fmaxf(c[o], 0.f);

    float d[32];
    #pragma unroll
    for (int o = 0; o < 32; o++) d[o] = bo2[o];
    #pragma unroll
    for (int k = 0; k < 32; k++){
        float ck = c[k];
        const float* w = Wo2 + k*32;
        #pragma unroll
        for (int o = 0; o < 32; o++) d[o] = fmaf(ck, w[o], d[o]);
    }
    float s = bo3[0];
    #pragma unroll
    for (int k = 0; k < 32; k++) s = fmaf(fmaxf(d[k], 0.f), Wo3[k], s);
    out[n] = s;
}

// ---------------- launch ----------------

extern "C" void kernel_launch(void* const* d_in, const int* in_sizes, int n_in,
                              void* d_out, int out_size, void* d_ws, size_t ws_size,
                              hipStream_t stream)
{
    (void)in_sizes; (void)n_in; (void)out_size; (void)ws_size;
    const float* consF = (const float*)d_in[0];
    const float* varsF = (const float*)d_in[1];
    const int*   eidx  = (const int*)d_in[2];
    const int*   eCons = eidx;
    const int*   eVars = eidx + E_N;

    const float* Wc  = (const float*)d_in[3],  *bc  = (const float*)d_in[4];
    const float* Wv  = (const float*)d_in[5],  *bv  = (const float*)d_in[6];
    const float* Wj1 = (const float*)d_in[7],  *bj1 = (const float*)d_in[8];
    const float* Wj2 = (const float*)d_in[9],  *bj2 = (const float*)d_in[10];
    const float* Wcr = (const float*)d_in[11], *bcr = (const float*)d_in[12];
    const float* Wvr = (const float*)d_in[13], *bvr = (const float*)d_in[14];
    const float* Wo1 = (const float*)d_in[15], *bo1 = (const float*)d_in[16];
    const float* Wo2 = (const float*)d_in[17], *bo2 = (const float*)d_in[18];
    const float* Wo3 = (const float*)d_in[19], *bo3 = (const float*)d_in[20];

    const size_t NT = (size_t)100000 * 32;
    float* c_emb = (float*)d_ws;            // [NC,32] -> out_c in place
    float* v_emb = c_emb + NT;              // [NV,32]
    float* P1    = v_emb + NT;              // v@W1v (pass1 var side / pass2 const side)
    float* P2    = P1 + NT;                 // c@W1c+b1 (pass1 const) / outc@W1c (pass2 var)
    float* accum = P2 + NT;                 // [N,32] segment sums
    unsigned* pbuf = (unsigned*)P2;         // overlay: 2E u32 over P2+accum (dead until CSR done)
    int*   cnt    = (int*)(accum + NT);     // [NKEY]
    int*   offs   = cnt + NKEY;             // [NKEY]
    int*   bcnt   = offs + NKEY;            // [NBKT]
    int*   bbase  = bcnt + NBKT;
    int*   bcur   = bbase + NBKT;
    int*   elist  = bcur + NBKT;            // [2E]
    __bf16* w2hi  = (__bf16*)(elist + 2*E_N);  // [2][64][8]
    __bf16* w2lo  = w2hi + 1024;

    const float* W1c = Wj1;                 // rows 0..31  (cons/out_c side)
    const float* W1v = Wj1 + 32*32;         // rows 32..63 (vars side)

    // --- two-level CSR build for BOTH directions ---
    hipMemsetAsync(bcnt, 0, (size_t)NBKT * 4, stream);
    k_bhist<<<dim3(12500), dim3(256), 0, stream>>>(eCons, eVars, bcnt);
    k_bscan<<<dim3(1), dim3(256), 0, stream>>>(bcnt, bbase, bcur);
    k_bucketA<<<dim3(12500), dim3(256), 0, stream>>>(eCons, eVars, bcur, pbuf);
    k_bucketB<<<dim3(NBKT), dim3(256), 0, stream>>>(pbuf, bbase, bcnt, cnt, offs, elist);
    k_w2prep<<<dim3(1), dim3(128), 0, stream>>>(Wj2, w2hi, w2lo);

    // --- embeddings + layer-1 hoist (P2 overwrite: pbuf is dead now) ---
    k_embed_cons<<<dim3(391), dim3(256), 0, stream>>>(consF, Wc, bc, c_emb);
    k_embed_vars<<<dim3(391), dim3(256), 0, stream>>>(varsF, Wv, bv, v_emb);
    k_mm32<<<dim3(391), dim3(256), 0, stream>>>(v_emb, W1v, nullptr, P1, NV_N);
    k_mm32<<<dim3(391), dim3(256), 0, stream>>>(c_emb, W1c, bj1, P2, NC_N);

    // ---- pass 1: edges -> constraints (keys [0,NC)) ----
    k_edge_mfma<<<dim3(25000), dim3(256), 0, stream>>>(
        P2, P1, offs, cnt, elist, w2hi, w2lo, bj2, accum, NC_N);
    k_consrep<<<dim3(391), dim3(256), 0, stream>>>(accum, c_emb, Wcr, bcr);

    // ---- pass 2: edges -> variables (keys [NC,NC+NV)) ----
    k_mm32<<<dim3(391), dim3(256), 0, stream>>>(c_emb, W1c, nullptr, P2, NC_N);
    k_badd<<<dim3(12500), dim3(256), 0, stream>>>(P1, bj1, NV_N);
    k_edge_mfma<<<dim3(25000), dim3(256), 0, stream>>>(
        P1, P2, offs + NC_N, cnt + NC_N, elist, w2hi, w2lo, bj2, accum, NV_N);
    k_out<<<dim3(391), dim3(256), 0, stream>>>(accum, v_emb, Wvr, bvr,
                                               Wo1, bo1, Wo2, bo2, Wo3, bo3,
                                               (float*)d_out);
}

// Round 6
// 448.236 us; speedup vs baseline: 4.4774x; 4.4774x over previous
//
#include <hip/hip_runtime.h>

#define NC_N 100000
#define NV_N 100000
#define E_N  3200000
#define NKEY 200000          // unified key space: [0,NC) cons, [NC,NC+NV) vars
#define NSB  196             // superbuckets of 1024 keys: ceil(200000/1024)
#define SBK  1024
#define NBLK_A 200
#define EPB  16000           // edges per phase-A block (200*16000 = E)

typedef __attribute__((ext_vector_type(8))) __bf16 bf16x8;
typedef __attribute__((ext_vector_type(4))) float  f32x4;

// ---------------- node embedding kernels ----------------

__global__ __launch_bounds__(256) void k_embed_cons(
    const float* __restrict__ f, const float* __restrict__ W,
    const float* __restrict__ b, float* __restrict__ out)
{
    int n = blockIdx.x * blockDim.x + threadIdx.x;
    if (n >= NC_N) return;
    float f0 = f[2*(size_t)n], f1 = f[2*(size_t)n + 1];
    float4* dst = (float4*)(out + (size_t)n * 32);
    #pragma unroll
    for (int q = 0; q < 8; q++){
        float4 r;
        #pragma unroll
        for (int j = 0; j < 4; j++){
            int o = q*4 + j;
            (&r.x)[j] = fmaxf(fmaf(f0, W[o], fmaf(f1, W[32 + o], b[o])), 0.f);
        }
        dst[q] = r;
    }
}

__global__ __launch_bounds__(256) void k_embed_vars(
    const float* __restrict__ f, const float* __restrict__ W,
    const float* __restrict__ b, float* __restrict__ out)
{
    int n = blockIdx.x * blockDim.x + threadIdx.x;
    if (n >= NV_N) return;
    float x[9];
    #pragma unroll
    for (int k = 0; k < 9; k++) x[k] = f[9*(size_t)n + k];
    float4* dst = (float4*)(out + (size_t)n * 32);
    #pragma unroll
    for (int q = 0; q < 8; q++){
        float4 r;
        #pragma unroll
        for (int j = 0; j < 4; j++){
            int o = q*4 + j;
            float s = b[o];
            #pragma unroll
            for (int k = 0; k < 9; k++) s = fmaf(x[k], W[k*32 + o], s);
            (&r.x)[j] = fmaxf(s, 0.f);
        }
        dst[q] = r;
    }
}

// out[N,32] = x[N,32] @ W[32,32] (+ bias, optional). No relu.
__global__ __launch_bounds__(256) void k_mm32(
    const float* __restrict__ x, const float* __restrict__ W,
    const float* __restrict__ bias, float* __restrict__ out, int n)
{
    int i = blockIdx.x * blockDim.x + threadIdx.x;
    if (i >= n) return;
    float h[32];
    if (bias){
        #pragma unroll
        for (int o = 0; o < 32; o++) h[o] = bias[o];
    } else {
        #pragma unroll
        for (int o = 0; o < 32; o++) h[o] = 0.f;
    }
    const float4* xp = (const float4*)(x + (size_t)i * 32);
    #pragma unroll
    for (int q = 0; q < 8; q++){
        float4 t = xp[q];
        #pragma unroll
        for (int j = 0; j < 4; j++){
            float xk = (&t.x)[j];
            const float* w = W + (q*4 + j)*32;
            #pragma unroll
            for (int o = 0; o < 32; o++) h[o] = fmaf(xk, w[o], h[o]);
        }
    }
    float4* dst = (float4*)(out + (size_t)i * 32);
    #pragma unroll
    for (int q = 0; q < 8; q++){
        float4 r;
        #pragma unroll
        for (int j = 0; j < 4; j++) (&r.x)[j] = h[q*4 + j];
        dst[q] = r;
    }
}

__global__ __launch_bounds__(256) void k_badd(
    float* __restrict__ P, const float* __restrict__ b, int n)
{
    int i = blockIdx.x * blockDim.x + threadIdx.x;
    if (i >= n * 32) return;
    P[i] += b[i & 31];
}

// ---------------- deterministic 3-phase counting sort ----------------

// phase A1: per-block superbucket histogram -> hists[sb*NBLK_A + blk]
__global__ __launch_bounds__(256) void k_sbhist(
    const int* __restrict__ eC, const int* __restrict__ eV, int* __restrict__ hists)
{
    __shared__ int lh[NSB];
    int t = threadIdx.x, blk = blockIdx.x;
    for (int i = t; i < NSB; i += 256) lh[i] = 0;
    __syncthreads();
    int base = blk * EPB;
    for (int i = base + t; i < base + EPB; i += 256){
        int kc = eC[i], kv = eV[i];
        atomicAdd(&lh[kc >> 10], 1);
        atomicAdd(&lh[(NC_N + kv) >> 10], 1);
    }
    __syncthreads();
    for (int i = t; i < NSB; i += 256) hists[i * NBLK_A + blk] = lh[i];
}

// phase A2a: per-superbucket scan over blocks -> partial run bases + totals
__global__ __launch_bounds__(256) void k_scanA(
    const int* __restrict__ hists, int* __restrict__ partial, int* __restrict__ total)
{
    __shared__ int s[256];
    int sb = blockIdx.x, t = threadIdx.x;
    int v = (t < NBLK_A) ? hists[sb * NBLK_A + t] : 0;
    s[t] = v;
    __syncthreads();
    #pragma unroll
    for (int d = 1; d < 256; d <<= 1){
        int u = (t >= d) ? s[t - d] : 0;
        __syncthreads();
        s[t] += u;
        __syncthreads();
    }
    if (t < NBLK_A) partial[sb * NBLK_A + t] = s[t] - v;   // exclusive
    if (t == 255) total[sb] = s[255];
}

// phase A2b: exclusive scan of superbucket totals -> bbase
__global__ __launch_bounds__(256) void k_scanB(
    const int* __restrict__ total, int* __restrict__ bbase)
{
    __shared__ int s[256];
    int t = threadIdx.x;
    int v = (t < NSB) ? total[t] : 0;
    s[t] = v;
    __syncthreads();
    #pragma unroll
    for (int d = 1; d < 256; d <<= 1){
        int u = (t >= d) ? s[t - d] : 0;
        __syncthreads();
        s[t] += u;
        __syncthreads();
    }
    if (t < NSB) bbase[t] = s[t] - v;
}

// phase A3: scatter packed entries into per-(block,superbucket) runs.
// Each pbuf cache line is written by exactly one block -> no cross-XCD
// partial-line writebacks. LDS atomics only.
__global__ __launch_bounds__(256) void k_sbscatter(
    const int* __restrict__ eC, const int* __restrict__ eV,
    const int* __restrict__ partial, const int* __restrict__ bbase,
    unsigned* __restrict__ pbuf)
{
    __shared__ int lcur[NSB];
    int t = threadIdx.x, blk = blockIdx.x;
    for (int i = t; i < NSB; i += 256) lcur[i] = bbase[i] + partial[i * NBLK_A + blk];
    __syncthreads();
    int base = blk * EPB;
    for (int i = base + t; i < base + EPB; i += 256){
        int kc = eC[i], kv = eV[i];
        int p1 = atomicAdd(&lcur[kc >> 10], 1);
        pbuf[p1] = ((unsigned)(kc & 1023) << 17) | (unsigned)kv;
        int gk = NC_N + kv;
        int p2 = atomicAdd(&lcur[gk >> 10], 1);
        pbuf[p2] = ((unsigned)(gk & 1023) << 17) | (unsigned)kc;
    }
}

// phase B: one block per superbucket. 1024-bin hist/scan -> cnt/offs for its
// keys, then scatter elist (random writes confined to this block's own window).
__global__ __launch_bounds__(256) void k_sbsort(
    const unsigned* __restrict__ pbuf, const int* __restrict__ bbase,
    const int* __restrict__ total, int* __restrict__ cnt,
    int* __restrict__ offs, int* __restrict__ elist)
{
    __shared__ int hist[SBK];
    __shared__ int cur[SBK];
    __shared__ int ts[256];
    int b = blockIdx.x, t = threadIdx.x;
    int base = bbase[b], n = total[b];
    for (int i = t; i < SBK; i += 256) hist[i] = 0;
    __syncthreads();
    for (int i = t; i < n; i += 256) atomicAdd(&hist[pbuf[base + i] >> 17], 1);
    __syncthreads();
    // blocked scan: thread t owns bins 4t..4t+3
    int h0 = hist[4*t], h1 = hist[4*t+1], h2 = hist[4*t+2], h3 = hist[4*t+3];
    int tsum = h0 + h1 + h2 + h3;
    ts[t] = tsum;
    __syncthreads();
    #pragma unroll
    for (int d = 1; d < 256; d <<= 1){
        int u = (t >= d) ? ts[t - d] : 0;
        __syncthreads();
        ts[t] += u;
        __syncthreads();
    }
    int e0 = ts[t] - tsum;
    int e1 = e0 + h0, e2 = e1 + h1, e3 = e2 + h2;
    cur[4*t]   = base + e0;
    cur[4*t+1] = base + e1;
    cur[4*t+2] = base + e2;
    cur[4*t+3] = base + e3;
    int g = b * SBK + 4*t;
    if (g   < NKEY){ cnt[g]   = h0; offs[g]   = base + e0; }
    if (g+1 < NKEY){ cnt[g+1] = h1; offs[g+1] = base + e1; }
    if (g+2 < NKEY){ cnt[g+2] = h2; offs[g+2] = base + e2; }
    if (g+3 < NKEY){ cnt[g+3] = h3; offs[g+3] = base + e3; }
    __syncthreads();
    for (int i = t; i < n; i += 256){
        unsigned p = pbuf[base + i];
        int pos = atomicAdd(&cur[p >> 17], 1);
        elist[pos] = (int)(p & 0x1FFFFu);
    }
}

// ---------------- W2 fragment prep (hi/lo bf16 split, MFMA B-layout) ----------
__global__ __launch_bounds__(128) void k_w2prep(
    const float* __restrict__ W2, __bf16* __restrict__ w2hi, __bf16* __restrict__ w2lo)
{
    int t = threadIdx.x;
    if (t >= 128) return;
    int h = t >> 6, l = t & 63;
    bf16x8 vh, vl;
    #pragma unroll
    for (int j = 0; j < 8; j++){
        float w = W2[((l >> 4) * 8 + j) * 32 + h * 16 + (l & 15)];
        __bf16 hi = (__bf16)w;
        vh[j] = hi;
        vl[j] = (__bf16)(w - (float)hi);
    }
    ((bf16x8*)w2hi)[t] = vh;
    ((bf16x8*)w2lo)[t] = vl;
}

// ---------------- MFMA edge pass: one wave per target node -------------------
__global__ __launch_bounds__(256) void k_edge_mfma(
    const float* __restrict__ Pconst, const float* __restrict__ Pvar,
    const int* __restrict__ offs, const int* __restrict__ cnt,
    const int* __restrict__ elist,
    const __bf16* __restrict__ w2hi, const __bf16* __restrict__ w2lo,
    const float* __restrict__ b2, float* __restrict__ accum, int n)
{
    int wid = (blockIdx.x * 256 + threadIdx.x) >> 6;
    int l   = threadIdx.x & 63;
    if (wid >= n) return;
    int row = l & 15;     // A-row (edge within tile) / C-col
    int kg  = l >> 4;     // k-chunk group

    bf16x8 wh0 = ((const bf16x8*)w2hi)[l];
    bf16x8 wh1 = ((const bf16x8*)w2hi)[64 + l];
    bf16x8 wl0 = ((const bf16x8*)w2lo)[l];
    bf16x8 wl1 = ((const bf16x8*)w2lo)[64 + l];
    float b2a = b2[row];
    float b2b = b2[16 + row];

    const float* pc = Pconst + (size_t)wid * 32 + kg * 8;
    f32x4 pc0 = *(const f32x4*)pc;
    f32x4 pc1 = *(const f32x4*)(pc + 4);

    int start = offs[wid], deg = cnt[wid];
    float acc0 = 0.f, acc1 = 0.f;
    int ntile = (deg + 15) >> 4;

    for (int t = 0; t < ntile; t++){
        int r  = t * 16 + row;
        int rc = (r < deg) ? r : (deg - 1);
        int other = elist[start + rc];
        const float* pv = Pvar + (size_t)other * 32 + kg * 8;
        f32x4 a0 = *(const f32x4*)pv;
        f32x4 a1 = *(const f32x4*)(pv + 4);

        bf16x8 ahi, alo;
        #pragma unroll
        for (int j = 0; j < 4; j++){
            float h0 = fmaxf(pc0[j] + a0[j], 0.f);
            float h1 = fmaxf(pc1[j] + a1[j], 0.f);
            __bf16 H0 = (__bf16)h0;
            __bf16 H1 = (__bf16)h1;
            ahi[j]     = H0;  alo[j]     = (__bf16)(h0 - (float)H0);
            ahi[4 + j] = H1;  alo[4 + j] = (__bf16)(h1 - (float)H1);
        }

        f32x4 c0 = {0.f, 0.f, 0.f, 0.f}, c1 = {0.f, 0.f, 0.f, 0.f};
        c0 = __builtin_amdgcn_mfma_f32_16x16x32_bf16(ahi, wh0, c0, 0, 0, 0);
        c0 = __builtin_amdgcn_mfma_f32_16x16x32_bf16(ahi, wl0, c0, 0, 0, 0);
        c0 = __builtin_amdgcn_mfma_f32_16x16x32_bf16(alo, wh0, c0, 0, 0, 0);
        c1 = __builtin_amdgcn_mfma_f32_16x16x32_bf16(ahi, wh1, c1, 0, 0, 0);
        c1 = __builtin_amdgcn_mfma_f32_16x16x32_bf16(ahi, wl1, c1, 0, 0, 0);
        c1 = __builtin_amdgcn_mfma_f32_16x16x32_bf16(alo, wh1, c1, 0, 0, 0);

        #pragma unroll
        for (int rr = 0; rr < 4; rr++){
            int er = t * 16 + kg * 4 + rr;   // C row = edge index
            if (er < deg){
                acc0 += fmaxf(c0[rr] + b2a, 0.f);
                acc1 += fmaxf(c1[rr] + b2b, 0.f);
            }
        }
    }

    acc0 += __shfl_xor(acc0, 16, 64);
    acc0 += __shfl_xor(acc0, 32, 64);
    acc1 += __shfl_xor(acc1, 16, 64);
    acc1 += __shfl_xor(acc1, 32, 64);

    if (l < 16)      accum[(size_t)wid * 32 + l] = acc0;       // cols 0..15
    else if (l < 32) accum[(size_t)wid * 32 + l] = acc1;       // cols 16..31
}

// ---------------- representation / output ----------------

__global__ __launch_bounds__(256) void k_consrep(
    const float* __restrict__ acc, float* __restrict__ cemb,
    const float* __restrict__ W, const float* __restrict__ b)
{
    int n = blockIdx.x * blockDim.x + threadIdx.x;
    if (n >= NC_N) return;
    float h[32];
    #pragma unroll
    for (int o = 0; o < 32; o++) h[o] = b[o];
    const float4* ap = (const float4*)(acc + (size_t)n * 32);
    #pragma unroll
    for (int q = 0; q < 8; q++){
        float4 t = ap[q];
        #pragma unroll
        for (int j = 0; j < 4; j++){
            float xk = (&t.x)[j];
            const float* w = W + (q*4 + j)*32;
            #pragma unroll
            for (int o = 0; o < 32; o++) h[o] = fmaf(xk, w[o], h[o]);
        }
    }
    const float4* cp = (const float4*)(cemb + (size_t)n * 32);
    #pragma unroll
    for (int q = 0; q < 8; q++){
        float4 t = cp[q];
        #pragma unroll
        for (int j = 0; j < 4; j++){
            float xk = (&t.x)[j];
            const float* w = W + (32 + q*4 + j)*32;
            #pragma unroll
            for (int o = 0; o < 32; o++) h[o] = fmaf(xk, w[o], h[o]);
        }
    }
    float4* dst = (float4*)(cemb + (size_t)n * 32);
    #pragma unroll
    for (int q = 0; q < 8; q++){
        float4 r;
        #pragma unroll
        for (int j = 0; j < 4; j++) (&r.x)[j] = fmaxf(h[q*4 + j], 0.f);
        dst[q] = r;
    }
}

__global__ __launch_bounds__(256) void k_out(
    const float* __restrict__ acc, const float* __restrict__ vemb,
    const float* __restrict__ Wvr, const float* __restrict__ bvr,
    const float* __restrict__ Wo1, const float* __restrict__ bo1,
    const float* __restrict__ Wo2, const float* __restrict__ bo2,
    const float* __restrict__ Wo3, const float* __restrict__ bo3,
    float* __restrict__ out)
{
    int n = blockIdx.x * blockDim.x + threadIdx.x;
    if (n >= NV_N) return;
    float a[32];
    #pragma unroll
    for (int o = 0; o < 32; o++) a[o] = bvr[o];
    const float4* ap = (const float4*)(acc + (size_t)n * 32);
    #pragma unroll
    for (int q = 0; q < 8; q++){
        float4 t = ap[q];
        #pragma unroll
        for (int j = 0; j < 4; j++){
            float xk = (&t.x)[j];
            const float* w = Wvr + (q*4 + j)*32;
            #pragma unroll
            for (int o = 0; o < 32; o++) a[o] = fmaf(xk, w[o], a[o]);
        }
    }
    const float4* vp = (const float4*)(vemb + (size_t)n * 32);
    #pragma unroll
    for (int q = 0; q < 8; q++){
        float4 t = vp[q];
        #pragma unroll
        for (int j = 0; j < 4; j++){
            float xk = (&t.x)[j];
            const float* w = Wvr + (32 + q*4 + j)*32;
            #pragma unroll
            for (int o = 0; o < 32; o++) a[o] = fmaf(xk, w[o], a[o]);
        }
    }
    #pragma unroll
    for (int o = 0; o < 32; o++) a[o] = fmaxf(a[o], 0.f);

    float c[32];
    #pragma unroll
    for (int o = 0; o < 32; o++) c[o] = bo1[o];
    #pragma unroll
    for (int k = 0; k < 32; k++){
        float ak = a[k];
        const float* w = Wo1 + k*32;
        #pragma unroll
        for (int o = 0; o < 32; o++) c[o] = fmaf(ak, w[o], c[o]);
    }
    #pragma unroll
    for (int o = 0; o < 32; o++) c[o] = fmaxf(c[o], 0.f);

    float d[32];
    #pragma unroll
    for (int o = 0; o < 32; o++) d[o] = bo2[o];
    #pragma unroll
    for (int k = 0; k < 32; k++){
        float ck = c[k];
        const float* w = Wo2 + k*32;
        #pragma unroll
        for (int o = 0; o < 32; o++) d[o] = fmaf(ck, w[o], d[o]);
    }
    float s = bo3[0];
    #pragma unroll
    for (int k = 0; k < 32; k++) s = fmaf(fmaxf(d[k], 0.f), Wo3[k], s);
    out[n] = s;
}

// ---------------- launch ----------------

extern "C" void kernel_launch(void* const* d_in, const int* in_sizes, int n_in,
                              void* d_out, int out_size, void* d_ws, size_t ws_size,
                              hipStream_t stream)
{
    (void)in_sizes; (void)n_in; (void)out_size; (void)ws_size;
    const float* consF = (const float*)d_in[0];
    const float* varsF = (const float*)d_in[1];
    const int*   eidx  = (const int*)d_in[2];
    const int*   eCons = eidx;
    const int*   eVars = eidx + E_N;

    const float* Wc  = (const float*)d_in[3],  *bc  = (const float*)d_in[4];
    const float* Wv  = (const float*)d_in[5],  *bv  = (const float*)d_in[6];
    const float* Wj1 = (const float*)d_in[7],  *bj1 = (const float*)d_in[8];
    const float* Wj2 = (const float*)d_in[9],  *bj2 = (const float*)d_in[10];
    const float* Wcr = (const float*)d_in[11], *bcr = (const float*)d_in[12];
    const float* Wvr = (const float*)d_in[13], *bvr = (const float*)d_in[14];
    const float* Wo1 = (const float*)d_in[15], *bo1 = (const float*)d_in[16];
    const float* Wo2 = (const float*)d_in[17], *bo2 = (const float*)d_in[18];
    const float* Wo3 = (const float*)d_in[19], *bo3 = (const float*)d_in[20];

    const size_t NT = (size_t)100000 * 32;
    float* c_emb = (float*)d_ws;            // [NC,32] -> out_c in place
    float* v_emb = c_emb + NT;              // [NV,32]
    float* P1    = v_emb + NT;              // v@W1v (pass1 var side / pass2 const side)
    float* P2    = P1 + NT;                 // c@W1c+b1 (pass1 const) / outc@W1c (pass2 var)
    float* accum = P2 + NT;                 // [N,32] segment sums
    unsigned* pbuf = (unsigned*)P2;         // overlay: 2E u32 over P2+accum (dead until sort done)
    int*   cnt     = (int*)(accum + NT);    // [NKEY]
    int*   offs    = cnt + NKEY;            // [NKEY]
    int*   hists   = offs + NKEY;           // [NSB*NBLK_A]
    int*   partial = hists + NSB*NBLK_A;    // [NSB*NBLK_A]
    int*   total   = partial + NSB*NBLK_A;  // [NSB]
    int*   bbase   = total + NSB;           // [NSB]
    int*   elist   = bbase + NSB;           // [2E]
    __bf16* w2hi   = (__bf16*)(elist + 2*E_N);  // [2][64][8]
    __bf16* w2lo   = w2hi + 1024;

    const float* W1c = Wj1;                 // rows 0..31  (cons/out_c side)
    const float* W1v = Wj1 + 32*32;         // rows 32..63 (vars side)

    // --- deterministic 3-phase counting sort for BOTH directions ---
    k_sbhist<<<dim3(NBLK_A), dim3(256), 0, stream>>>(eCons, eVars, hists);
    k_scanA<<<dim3(NSB), dim3(256), 0, stream>>>(hists, partial, total);
    k_scanB<<<dim3(1), dim3(256), 0, stream>>>(total, bbase);
    k_sbscatter<<<dim3(NBLK_A), dim3(256), 0, stream>>>(eCons, eVars, partial, bbase, pbuf);
    k_sbsort<<<dim3(NSB), dim3(256), 0, stream>>>(pbuf, bbase, total, cnt, offs, elist);
    k_w2prep<<<dim3(1), dim3(128), 0, stream>>>(Wj2, w2hi, w2lo);

    // --- embeddings + layer-1 hoist (P2 overwrite: pbuf is dead now) ---
    k_embed_cons<<<dim3(391), dim3(256), 0, stream>>>(consF, Wc, bc, c_emb);
    k_embed_vars<<<dim3(391), dim3(256), 0, stream>>>(varsF, Wv, bv, v_emb);
    k_mm32<<<dim3(391), dim3(256), 0, stream>>>(v_emb, W1v, nullptr, P1, NV_N);
    k_mm32<<<dim3(391), dim3(256), 0, stream>>>(c_emb, W1c, bj1, P2, NC_N);

    // ---- pass 1: edges -> constraints (keys [0,NC)) ----
    k_edge_mfma<<<dim3(25000), dim3(256), 0, stream>>>(
        P2, P1, offs, cnt, elist, w2hi, w2lo, bj2, accum, NC_N);
    k_consrep<<<dim3(391), dim3(256), 0, stream>>>(accum, c_emb, Wcr, bcr);

    // ---- pass 2: edges -> variables (keys [NC,NC+NV)) ----
    k_mm32<<<dim3(391), dim3(256), 0, stream>>>(c_emb, W1c, nullptr, P2, NC_N);
    k_badd<<<dim3(12500), dim3(256), 0, stream>>>(P1, bj1, NV_N);
    k_edge_mfma<<<dim3(25000), dim3(256), 0, stream>>>(
        P1, P2, offs + NC_N, cnt + NC_N, elist, w2hi, w2lo, bj2, accum, NV_N);
    k_out<<<dim3(391), dim3(256), 0, stream>>>(accum, v_emb, Wvr, bvr,
                                               Wo1, bo1, Wo2, bo2, Wo3, bo3,
                                               (float*)d_out);
}

// Round 7
// 390.295 us; speedup vs baseline: 5.1421x; 1.1485x over previous
//
#include <hip/hip_runtime.h>

#define NC_N 100000
#define NV_N 100000
#define E_N  3200000
#define NKEY 200000          // unified key space: [0,NC) cons, [NC,NC+NV) vars
#define SBK  512             // keys per superbucket
#define NSB  391             // ceil(200000/512)
#define SCAP 18432           // per-superbucket capacity (mean 16368, sigma ~128)
#define NBLK_A 200
#define EPB  16000           // edges per phase-A block (200*16000 = E)

typedef __attribute__((ext_vector_type(8))) __bf16 bf16x8;
typedef __attribute__((ext_vector_type(4))) float  f32x4;

// ---------------- fused node embedding kernels ----------------

// c = relu(cons_features @ Wc + bc); write c_emb AND P = c @ W1c (no bias)
__global__ __launch_bounds__(256) void k_embed_cons_f(
    const float* __restrict__ f, const float* __restrict__ Wc,
    const float* __restrict__ bc, const float* __restrict__ W1c,
    float* __restrict__ c_emb, float* __restrict__ P)
{
    int n = blockIdx.x * blockDim.x + threadIdx.x;
    if (n >= NC_N) return;
    float f0 = f[2*(size_t)n], f1 = f[2*(size_t)n + 1];
    float c[32];
    #pragma unroll
    for (int o = 0; o < 32; o++)
        c[o] = fmaxf(fmaf(f0, Wc[o], fmaf(f1, Wc[32 + o], bc[o])), 0.f);
    float4* dc = (float4*)(c_emb + (size_t)n * 32);
    #pragma unroll
    for (int q = 0; q < 8; q++){
        float4 r;
        #pragma unroll
        for (int j = 0; j < 4; j++) (&r.x)[j] = c[q*4 + j];
        dc[q] = r;
    }
    float p[32];
    #pragma unroll
    for (int o = 0; o < 32; o++) p[o] = 0.f;
    #pragma unroll
    for (int k = 0; k < 32; k++){
        float ck = c[k];
        const float* w = W1c + k*32;
        #pragma unroll
        for (int o = 0; o < 32; o++) p[o] = fmaf(ck, w[o], p[o]);
    }
    float4* dp = (float4*)(P + (size_t)n * 32);
    #pragma unroll
    for (int q = 0; q < 8; q++){
        float4 r;
        #pragma unroll
        for (int j = 0; j < 4; j++) (&r.x)[j] = p[q*4 + j];
        dp[q] = r;
    }
}

// v = relu(vars_features @ Wv + bv); write v_emb AND P = v @ W1v (no bias)
__global__ __launch_bounds__(256) void k_embed_vars_f(
    const float* __restrict__ f, const float* __restrict__ Wv,
    const float* __restrict__ bv, const float* __restrict__ W1v,
    float* __restrict__ v_emb, float* __restrict__ P)
{
    int n = blockIdx.x * blockDim.x + threadIdx.x;
    if (n >= NV_N) return;
    float x[9];
    #pragma unroll
    for (int k = 0; k < 9; k++) x[k] = f[9*(size_t)n + k];
    float v[32];
    #pragma unroll
    for (int o = 0; o < 32; o++){
        float s = bv[o];
        #pragma unroll
        for (int k = 0; k < 9; k++) s = fmaf(x[k], Wv[k*32 + o], s);
        v[o] = fmaxf(s, 0.f);
    }
    float4* dv = (float4*)(v_emb + (size_t)n * 32);
    #pragma unroll
    for (int q = 0; q < 8; q++){
        float4 r;
        #pragma unroll
        for (int j = 0; j < 4; j++) (&r.x)[j] = v[q*4 + j];
        dv[q] = r;
    }
    float p[32];
    #pragma unroll
    for (int o = 0; o < 32; o++) p[o] = 0.f;
    #pragma unroll
    for (int k = 0; k < 32; k++){
        float vk = v[k];
        const float* w = W1v + k*32;
        #pragma unroll
        for (int o = 0; o < 32; o++) p[o] = fmaf(vk, w[o], p[o]);
    }
    float4* dp = (float4*)(P + (size_t)n * 32);
    #pragma unroll
    for (int q = 0; q < 8; q++){
        float4 r;
        #pragma unroll
        for (int j = 0; j < 4; j++) (&r.x)[j] = p[q*4 + j];
        dp[q] = r;
    }
}

// ---------------- deterministic 3-phase counting sort ----------------

__global__ __launch_bounds__(256) void k_sbhist(
    const int* __restrict__ eC, const int* __restrict__ eV, int* __restrict__ hists)
{
    __shared__ int lh[NSB];
    int t = threadIdx.x, blk = blockIdx.x;
    for (int i = t; i < NSB; i += 256) lh[i] = 0;
    __syncthreads();
    int base = blk * EPB;
    for (int i = base + t; i < base + EPB; i += 256){
        int kc = eC[i], kv = eV[i];
        atomicAdd(&lh[kc >> 9], 1);
        atomicAdd(&lh[(NC_N + kv) >> 9], 1);
    }
    __syncthreads();
    for (int i = t; i < NSB; i += 256) hists[i * NBLK_A + blk] = lh[i];
}

__global__ __launch_bounds__(256) void k_scanA(
    const int* __restrict__ hists, int* __restrict__ partial, int* __restrict__ total)
{
    __shared__ int s[256];
    int sb = blockIdx.x, t = threadIdx.x;
    int v = (t < NBLK_A) ? hists[sb * NBLK_A + t] : 0;
    s[t] = v;
    __syncthreads();
    #pragma unroll
    for (int d = 1; d < 256; d <<= 1){
        int u = (t >= d) ? s[t - d] : 0;
        __syncthreads();
        s[t] += u;
        __syncthreads();
    }
    if (t < NBLK_A) partial[sb * NBLK_A + t] = s[t] - v;   // exclusive
    if (t == 255) total[sb] = s[255];
}

__global__ __launch_bounds__(512) void k_scanB(
    const int* __restrict__ total, int* __restrict__ bbase)
{
    __shared__ int s[512];
    int t = threadIdx.x;
    int v = (t < NSB) ? total[t] : 0;
    s[t] = v;
    __syncthreads();
    #pragma unroll
    for (int d = 1; d < 512; d <<= 1){
        int u = (t >= d) ? s[t - d] : 0;
        __syncthreads();
        s[t] += u;
        __syncthreads();
    }
    if (t < NSB) bbase[t] = s[t] - v;
}

// phase A3: single-writer runs per (block,superbucket); LDS atomics only
__global__ __launch_bounds__(256) void k_sbscatter(
    const int* __restrict__ eC, const int* __restrict__ eV,
    const int* __restrict__ partial, const int* __restrict__ bbase,
    unsigned* __restrict__ pbuf)
{
    __shared__ int lcur[NSB];
    int t = threadIdx.x, blk = blockIdx.x;
    for (int i = t; i < NSB; i += 256) lcur[i] = bbase[i] + partial[i * NBLK_A + blk];
    __syncthreads();
    int base = blk * EPB;
    for (int i = base + t; i < base + EPB; i += 256){
        int kc = eC[i], kv = eV[i];
        int p1 = atomicAdd(&lcur[kc >> 9], 1);
        pbuf[p1] = ((unsigned)(kc & 511) << 17) | (unsigned)kv;
        int gk = NC_N + kv;
        int p2 = atomicAdd(&lcur[gk >> 9], 1);
        pbuf[p2] = ((unsigned)(gk & 511) << 17) | (unsigned)kc;
    }
}

// phase B: one block per superbucket; 512-bin hist/scan -> cnt/offs; LDS-staged
// permute; fully COALESCED elist write (no global scatter).
__global__ __launch_bounds__(256) void k_sbsort(
    const unsigned* __restrict__ pbuf, const int* __restrict__ bbase,
    const int* __restrict__ total, int* __restrict__ cnt,
    int* __restrict__ offs, int* __restrict__ elist)
{
    __shared__ int sout[SCAP];
    __shared__ int hist[SBK];
    __shared__ int cur[SBK];
    __shared__ int ts[256];
    int b = blockIdx.x, t = threadIdx.x;
    int base = bbase[b], n = total[b];
    if (n > SCAP) n = SCAP;             // safety clamp (never hit for this input)
    for (int i = t; i < SBK; i += 256) hist[i] = 0;
    __syncthreads();
    for (int i = t; i < n; i += 256) atomicAdd(&hist[pbuf[base + i] >> 17], 1);
    __syncthreads();
    // blocked scan: thread t owns bins 2t, 2t+1
    int h0 = hist[2*t], h1 = hist[2*t+1];
    int tsum = h0 + h1;
    ts[t] = tsum;
    __syncthreads();
    #pragma unroll
    for (int d = 1; d < 256; d <<= 1){
        int u = (t >= d) ? ts[t - d] : 0;
        __syncthreads();
        ts[t] += u;
        __syncthreads();
    }
    int e0 = ts[t] - tsum;
    int e1 = e0 + h0;
    cur[2*t]   = e0;                    // LOCAL offsets into sout
    cur[2*t+1] = e1;
    int g = b * SBK + 2*t;
    if (g   < NKEY){ cnt[g]   = h0; offs[g]   = base + e0; }
    if (g+1 < NKEY){ cnt[g+1] = h1; offs[g+1] = base + e1; }
    __syncthreads();
    for (int i = t; i < n; i += 256){
        unsigned p = pbuf[base + i];
        int pos = atomicAdd(&cur[p >> 17], 1);
        sout[pos] = (int)(p & 0x1FFFFu);
    }
    __syncthreads();
    for (int i = t; i < n; i += 256) elist[base + i] = sout[i];
}

// ---------------- W2 fragment prep (hi/lo bf16 split, MFMA B-layout) ----------
__global__ __launch_bounds__(128) void k_w2prep(
    const float* __restrict__ W2, __bf16* __restrict__ w2hi, __bf16* __restrict__ w2lo)
{
    int t = threadIdx.x;
    if (t >= 128) return;
    int h = t >> 6, l = t & 63;
    bf16x8 vh, vl;
    #pragma unroll
    for (int j = 0; j < 8; j++){
        float w = W2[((l >> 4) * 8 + j) * 32 + h * 16 + (l & 15)];
        __bf16 hi = (__bf16)w;
        vh[j] = hi;
        vl[j] = (__bf16)(w - (float)hi);
    }
    ((bf16x8*)w2hi)[t] = vh;
    ((bf16x8*)w2lo)[t] = vl;
}

// ---------------- MFMA edge pass: one wave per target node -------------------
// h_e = relu(Pconst[node] + b1 + Pvar[other_e]); G = H @ W2 (hi/lo bf16 MFMA);
// acc[node][col] = sum_e relu(G[e][col] + b2[col]).
__global__ __launch_bounds__(256) void k_edge_mfma(
    const float* __restrict__ Pconst, const float* __restrict__ Pvar,
    const int* __restrict__ offs, const int* __restrict__ cnt,
    const int* __restrict__ elist,
    const __bf16* __restrict__ w2hi, const __bf16* __restrict__ w2lo,
    const float* __restrict__ b1, const float* __restrict__ b2,
    float* __restrict__ accum, int n)
{
    int wid = (blockIdx.x * 256 + threadIdx.x) >> 6;
    int l   = threadIdx.x & 63;
    if (wid >= n) return;
    int row = l & 15;     // A-row (edge within tile) / C-col
    int kg  = l >> 4;     // k-chunk group

    bf16x8 wh0 = ((const bf16x8*)w2hi)[l];
    bf16x8 wh1 = ((const bf16x8*)w2hi)[64 + l];
    bf16x8 wl0 = ((const bf16x8*)w2lo)[l];
    bf16x8 wl1 = ((const bf16x8*)w2lo)[64 + l];
    float b2a = b2[row];
    float b2b = b2[16 + row];

    const float* pc = Pconst + (size_t)wid * 32 + kg * 8;
    const float* pb = b1 + kg * 8;
    f32x4 pc0 = *(const f32x4*)pc + *(const f32x4*)pb;
    f32x4 pc1 = *(const f32x4*)(pc + 4) + *(const f32x4*)(pb + 4);

    int start = offs[wid], deg = cnt[wid];
    float acc0 = 0.f, acc1 = 0.f;
    int ntile = (deg + 15) >> 4;

    for (int t = 0; t < ntile; t++){
        int r  = t * 16 + row;
        int rc = (r < deg) ? r : (deg - 1);
        int other = elist[start + rc];
        const float* pv = Pvar + (size_t)other * 32 + kg * 8;
        f32x4 a0 = *(const f32x4*)pv;
        f32x4 a1 = *(const f32x4*)(pv + 4);

        bf16x8 ahi, alo;
        #pragma unroll
        for (int j = 0; j < 4; j++){
            float h0 = fmaxf(pc0[j] + a0[j], 0.f);
            float h1 = fmaxf(pc1[j] + a1[j], 0.f);
            __bf16 H0 = (__bf16)h0;
            __bf16 H1 = (__bf16)h1;
            ahi[j]     = H0;  alo[j]     = (__bf16)(h0 - (float)H0);
            ahi[4 + j] = H1;  alo[4 + j] = (__bf16)(h1 - (float)H1);
        }

        f32x4 c0 = {0.f, 0.f, 0.f, 0.f}, c1 = {0.f, 0.f, 0.f, 0.f};
        c0 = __builtin_amdgcn_mfma_f32_16x16x32_bf16(ahi, wh0, c0, 0, 0, 0);
        c0 = __builtin_amdgcn_mfma_f32_16x16x32_bf16(ahi, wl0, c0, 0, 0, 0);
        c0 = __builtin_amdgcn_mfma_f32_16x16x32_bf16(alo, wh0, c0, 0, 0, 0);
        c1 = __builtin_amdgcn_mfma_f32_16x16x32_bf16(ahi, wh1, c1, 0, 0, 0);
        c1 = __builtin_amdgcn_mfma_f32_16x16x32_bf16(ahi, wl1, c1, 0, 0, 0);
        c1 = __builtin_amdgcn_mfma_f32_16x16x32_bf16(alo, wh1, c1, 0, 0, 0);

        #pragma unroll
        for (int rr = 0; rr < 4; rr++){
            int er = t * 16 + kg * 4 + rr;   // C row = edge index
            if (er < deg){
                acc0 += fmaxf(c0[rr] + b2a, 0.f);
                acc1 += fmaxf(c1[rr] + b2b, 0.f);
            }
        }
    }

    acc0 += __shfl_xor(acc0, 16, 64);
    acc0 += __shfl_xor(acc0, 32, 64);
    acc1 += __shfl_xor(acc1, 16, 64);
    acc1 += __shfl_xor(acc1, 32, 64);

    if (l < 16)      accum[(size_t)wid * 32 + l] = acc0;       // cols 0..15
    else if (l < 32) accum[(size_t)wid * 32 + l] = acc1;       // cols 16..31
}

// ---------------- fused representation / output ----------------

// out_c = relu(concat(acc, c) @ Wcr + bcr) -> cemb (in place) AND P = out_c @ W1c
__global__ __launch_bounds__(256) void k_consrep_f(
    const float* __restrict__ acc, float* __restrict__ cemb,
    const float* __restrict__ Wcr, const float* __restrict__ bcr,
    const float* __restrict__ W1c, float* __restrict__ P)
{
    int n = blockIdx.x * blockDim.x + threadIdx.x;
    if (n >= NC_N) return;
    float h[32];
    #pragma unroll
    for (int o = 0; o < 32; o++) h[o] = bcr[o];
    const float4* ap = (const float4*)(acc + (size_t)n * 32);
    #pragma unroll
    for (int q = 0; q < 8; q++){
        float4 t = ap[q];
        #pragma unroll
        for (int j = 0; j < 4; j++){
            float xk = (&t.x)[j];
            const float* w = Wcr + (q*4 + j)*32;
            #pragma unroll
            for (int o = 0; o < 32; o++) h[o] = fmaf(xk, w[o], h[o]);
        }
    }
    const float4* cp = (const float4*)(cemb + (size_t)n * 32);
    #pragma unroll
    for (int q = 0; q < 8; q++){
        float4 t = cp[q];
        #pragma unroll
        for (int j = 0; j < 4; j++){
            float xk = (&t.x)[j];
            const float* w = Wcr + (32 + q*4 + j)*32;
            #pragma unroll
            for (int o = 0; o < 32; o++) h[o] = fmaf(xk, w[o], h[o]);
        }
    }
    #pragma unroll
    for (int o = 0; o < 32; o++) h[o] = fmaxf(h[o], 0.f);
    float4* dst = (float4*)(cemb + (size_t)n * 32);
    #pragma unroll
    for (int q = 0; q < 8; q++){
        float4 r;
        #pragma unroll
        for (int j = 0; j < 4; j++) (&r.x)[j] = h[q*4 + j];
        dst[q] = r;
    }
    float p[32];
    #pragma unroll
    for (int o = 0; o < 32; o++) p[o] = 0.f;
    #pragma unroll
    for (int k = 0; k < 32; k++){
        float hk = h[k];
        const float* w = W1c + k*32;
        #pragma unroll
        for (int o = 0; o < 32; o++) p[o] = fmaf(hk, w[o], p[o]);
    }
    float4* dp = (float4*)(P + (size_t)n * 32);
    #pragma unroll
    for (int q = 0; q < 8; q++){
        float4 r;
        #pragma unroll
        for (int j = 0; j < 4; j++) (&r.x)[j] = p[q*4 + j];
        dp[q] = r;
    }
}

__global__ __launch_bounds__(256) void k_out(
    const float* __restrict__ acc, const float* __restrict__ vemb,
    const float* __restrict__ Wvr, const float* __restrict__ bvr,
    const float* __restrict__ Wo1, const float* __restrict__ bo1,
    const float* __restrict__ Wo2, const float* __restrict__ bo2,
    const float* __restrict__ Wo3, const float* __restrict__ bo3,
    float* __restrict__ out)
{
    int n = blockIdx.x * blockDim.x + threadIdx.x;
    if (n >= NV_N) return;
    float a[32];
    #pragma unroll
    for (int o = 0; o < 32; o++) a[o] = bvr[o];
    const float4* ap = (const float4*)(acc + (size_t)n * 32);
    #pragma unroll
    for (int q = 0; q < 8; q++){
        float4 t = ap[q];
        #pragma unroll
        for (int j = 0; j < 4; j++){
            float xk = (&t.x)[j];
            const float* w = Wvr + (q*4 + j)*32;
            #pragma unroll
            for (int o = 0; o < 32; o++) a[o] = fmaf(xk, w[o], a[o]);
        }
    }
    const float4* vp = (const float4*)(vemb + (size_t)n * 32);
    #pragma unroll
    for (int q = 0; q < 8; q++){
        float4 t = vp[q];
        #pragma unroll
        for (int j = 0; j < 4; j++){
            float xk = (&t.x)[j];
            const float* w = Wvr + (32 + q*4 + j)*32;
            #pragma unroll
            for (int o = 0; o < 32; o++) a[o] = fmaf(xk, w[o], a[o]);
        }
    }
    #pragma unroll
    for (int o = 0; o < 32; o++) a[o] = fmaxf(a[o], 0.f);

    float c[32];
    #pragma unroll
    for (int o = 0; o < 32; o++) c[o] = bo1[o];
    #pragma unroll
    for (int k = 0; k < 32; k++){
        float ak = a[k];
        const float* w = Wo1 + k*32;
        #pragma unroll
        for (int o = 0; o < 32; o++) c[o] = fmaf(ak, w[o], c[o]);
    }
    #pragma unroll
    for (int o = 0; o < 32; o++) c[o] = fmaxf(c[o], 0.f);

    float d[32];
    #pragma unroll
    for (int o = 0; o < 32; o++) d[o] = bo2[o];
    #pragma unroll
    for (int k = 0; k < 32; k++){
        float ck = c[k];
        const float* w = Wo2 + k*32;
        #pragma unroll
        for (int o = 0; o < 32; o++) d[o] = fmaf(ck, w[o], d[o]);
    }
    float s = bo3[0];
    #pragma unroll
    for (int k = 0; k < 32; k++) s = fmaf(fmaxf(d[k], 0.f), Wo3[k], s);
    out[n] = s;
}

// ---------------- launch ----------------

extern "C" void kernel_launch(void* const* d_in, const int* in_sizes, int n_in,
                              void* d_out, int out_size, void* d_ws, size_t ws_size,
                              hipStream_t stream)
{
    (void)in_sizes; (void)n_in; (void)out_size; (void)ws_size;
    const float* consF = (const float*)d_in[0];
    const float* varsF = (const float*)d_in[1];
    const int*   eidx  = (const int*)d_in[2];
    const int*   eCons = eidx;
    const int*   eVars = eidx + E_N;

    const float* Wc  = (const float*)d_in[3],  *bc  = (const float*)d_in[4];
    const float* Wv  = (const float*)d_in[5],  *bv  = (const float*)d_in[6];
    const float* Wj1 = (const float*)d_in[7],  *bj1 = (const float*)d_in[8];
    const float* Wj2 = (const float*)d_in[9],  *bj2 = (const float*)d_in[10];
    const float* Wcr = (const float*)d_in[11], *bcr = (const float*)d_in[12];
    const float* Wvr = (const float*)d_in[13], *bvr = (const float*)d_in[14];
    const float* Wo1 = (const float*)d_in[15], *bo1 = (const float*)d_in[16];
    const float* Wo2 = (const float*)d_in[17], *bo2 = (const float*)d_in[18];
    const float* Wo3 = (const float*)d_in[19], *bo3 = (const float*)d_in[20];

    const size_t NT = (size_t)100000 * 32;
    float* c_emb = (float*)d_ws;            // [NC,32] -> out_c in place
    float* v_emb = c_emb + NT;              // [NV,32]
    float* P1    = v_emb + NT;              // v@W1v (var side pass1 / const side pass2)
    float* P2    = P1 + NT;                 // c@W1c (pass1 const) / outc@W1c (pass2 var)
    float* accum = P2 + NT;                 // [N,32] segment sums
    unsigned* pbuf = (unsigned*)P2;         // overlay: 2E u32 over P2+accum (dead until sort done)
    int*   cnt     = (int*)(accum + NT);    // [NKEY]
    int*   offs    = cnt + NKEY;            // [NKEY]
    int*   hists   = offs + NKEY;           // [NSB*NBLK_A]
    int*   partial = hists + NSB*NBLK_A;    // [NSB*NBLK_A]
    int*   total   = partial + NSB*NBLK_A;  // [NSB]
    int*   bbase   = total + NSB;           // [NSB]
    int*   elist   = bbase + NSB;           // [2E]
    __bf16* w2hi   = (__bf16*)(elist + 2*E_N);  // [2][64][8]
    __bf16* w2lo   = w2hi + 1024;

    const float* W1c = Wj1;                 // rows 0..31  (cons/out_c side)
    const float* W1v = Wj1 + 32*32;         // rows 32..63 (vars side)

    // --- deterministic 3-phase counting sort for BOTH directions ---
    k_sbhist<<<dim3(NBLK_A), dim3(256), 0, stream>>>(eCons, eVars, hists);
    k_scanA<<<dim3(NSB), dim3(256), 0, stream>>>(hists, partial, total);
    k_scanB<<<dim3(1), dim3(512), 0, stream>>>(total, bbase);
    k_sbscatter<<<dim3(NBLK_A), dim3(256), 0, stream>>>(eCons, eVars, partial, bbase, pbuf);
    k_sbsort<<<dim3(NSB), dim3(256), 0, stream>>>(pbuf, bbase, total, cnt, offs, elist);
    k_w2prep<<<dim3(1), dim3(128), 0, stream>>>(Wj2, w2hi, w2lo);

    // --- fused embeddings + layer-1 hoist (P2 overwrite: pbuf is dead now) ---
    k_embed_cons_f<<<dim3(391), dim3(256), 0, stream>>>(consF, Wc, bc, W1c, c_emb, P2);
    k_embed_vars_f<<<dim3(391), dim3(256), 0, stream>>>(varsF, Wv, bv, W1v, v_emb, P1);

    // ---- pass 1: edges -> constraints (keys [0,NC)) ----
    k_edge_mfma<<<dim3(25000), dim3(256), 0, stream>>>(
        P2, P1, offs, cnt, elist, w2hi, w2lo, bj1, bj2, accum, NC_N);
    k_consrep_f<<<dim3(391), dim3(256), 0, stream>>>(accum, c_emb, Wcr, bcr, W1c, P2);

    // ---- pass 2: edges -> variables (keys [NC,NC+NV)) ----
    k_edge_mfma<<<dim3(25000), dim3(256), 0, stream>>>(
        P1, P2, offs + NC_N, cnt + NC_N, elist, w2hi, w2lo, bj1, bj2, accum, NV_N);
    k_out<<<dim3(391), dim3(256), 0, stream>>>(accum, v_emb, Wvr, bvr,
                                               Wo1, bo1, Wo2, bo2, Wo3, bo3,
                                               (float*)d_out);
}

// Round 8
// 353.041 us; speedup vs baseline: 5.6847x; 1.1055x over previous
//
#include <hip/hip_runtime.h>

#define NC_N 100000
#define NV_N 100000
#define E_N  3200000
#define NKEY 200000          // unified key space: [0,NC) cons, [NC,NC+NV) vars
#define SBK  512             // keys per superbucket
#define NSB  391             // ceil(200000/512)
#define SCAP 18432           // per-superbucket capacity (mean 16368, sigma ~128)
#define NBLK_A 200
#define EPB  16000           // edges per phase-A block (200*16000 = E)

typedef __attribute__((ext_vector_type(8))) __bf16    bf16x8;
typedef __attribute__((ext_vector_type(8))) _Float16  f16x8;
typedef __attribute__((ext_vector_type(4))) float     f32x4;

// ---------------- fused node embedding kernels ----------------

// c = relu(cons_features @ Wc + bc); write c_emb (f32) AND P = c @ W1c (fp16)
__global__ __launch_bounds__(256) void k_embed_cons_f(
    const float* __restrict__ f, const float* __restrict__ Wc,
    const float* __restrict__ bc, const float* __restrict__ W1c,
    float* __restrict__ c_emb, _Float16* __restrict__ P)
{
    int n = blockIdx.x * blockDim.x + threadIdx.x;
    if (n >= NC_N) return;
    float f0 = f[2*(size_t)n], f1 = f[2*(size_t)n + 1];
    float c[32];
    #pragma unroll
    for (int o = 0; o < 32; o++)
        c[o] = fmaxf(fmaf(f0, Wc[o], fmaf(f1, Wc[32 + o], bc[o])), 0.f);
    float4* dc = (float4*)(c_emb + (size_t)n * 32);
    #pragma unroll
    for (int q = 0; q < 8; q++){
        float4 r;
        #pragma unroll
        for (int j = 0; j < 4; j++) (&r.x)[j] = c[q*4 + j];
        dc[q] = r;
    }
    float p[32];
    #pragma unroll
    for (int o = 0; o < 32; o++) p[o] = 0.f;
    #pragma unroll
    for (int k = 0; k < 32; k++){
        float ck = c[k];
        const float* w = W1c + k*32;
        #pragma unroll
        for (int o = 0; o < 32; o++) p[o] = fmaf(ck, w[o], p[o]);
    }
    f16x8* dp = (f16x8*)(P + (size_t)n * 32);
    #pragma unroll
    for (int q = 0; q < 4; q++){
        f16x8 r;
        #pragma unroll
        for (int j = 0; j < 8; j++) r[j] = (_Float16)p[q*8 + j];
        dp[q] = r;
    }
}

// v = relu(vars_features @ Wv + bv); write v_emb (f32) AND P = v @ W1v (fp16)
__global__ __launch_bounds__(256) void k_embed_vars_f(
    const float* __restrict__ f, const float* __restrict__ Wv,
    const float* __restrict__ bv, const float* __restrict__ W1v,
    float* __restrict__ v_emb, _Float16* __restrict__ P)
{
    int n = blockIdx.x * blockDim.x + threadIdx.x;
    if (n >= NV_N) return;
    float x[9];
    #pragma unroll
    for (int k = 0; k < 9; k++) x[k] = f[9*(size_t)n + k];
    float v[32];
    #pragma unroll
    for (int o = 0; o < 32; o++){
        float s = bv[o];
        #pragma unroll
        for (int k = 0; k < 9; k++) s = fmaf(x[k], Wv[k*32 + o], s);
        v[o] = fmaxf(s, 0.f);
    }
    float4* dv = (float4*)(v_emb + (size_t)n * 32);
    #pragma unroll
    for (int q = 0; q < 8; q++){
        float4 r;
        #pragma unroll
        for (int j = 0; j < 4; j++) (&r.x)[j] = v[q*4 + j];
        dv[q] = r;
    }
    float p[32];
    #pragma unroll
    for (int o = 0; o < 32; o++) p[o] = 0.f;
    #pragma unroll
    for (int k = 0; k < 32; k++){
        float vk = v[k];
        const float* w = W1v + k*32;
        #pragma unroll
        for (int o = 0; o < 32; o++) p[o] = fmaf(vk, w[o], p[o]);
    }
    f16x8* dp = (f16x8*)(P + (size_t)n * 32);
    #pragma unroll
    for (int q = 0; q < 4; q++){
        f16x8 r;
        #pragma unroll
        for (int j = 0; j < 8; j++) r[j] = (_Float16)p[q*8 + j];
        dp[q] = r;
    }
}

// ---------------- deterministic 3-phase counting sort ----------------

__global__ __launch_bounds__(256) void k_sbhist(
    const int* __restrict__ eC, const int* __restrict__ eV, int* __restrict__ hists)
{
    __shared__ int lh[NSB];
    int t = threadIdx.x, blk = blockIdx.x;
    for (int i = t; i < NSB; i += 256) lh[i] = 0;
    __syncthreads();
    int base = blk * EPB;
    for (int i = base + t; i < base + EPB; i += 256){
        int kc = eC[i], kv = eV[i];
        atomicAdd(&lh[kc >> 9], 1);
        atomicAdd(&lh[(NC_N + kv) >> 9], 1);
    }
    __syncthreads();
    for (int i = t; i < NSB; i += 256) hists[i * NBLK_A + blk] = lh[i];
}

__global__ __launch_bounds__(256) void k_scanA(
    const int* __restrict__ hists, int* __restrict__ partial, int* __restrict__ total)
{
    __shared__ int s[256];
    int sb = blockIdx.x, t = threadIdx.x;
    int v = (t < NBLK_A) ? hists[sb * NBLK_A + t] : 0;
    s[t] = v;
    __syncthreads();
    #pragma unroll
    for (int d = 1; d < 256; d <<= 1){
        int u = (t >= d) ? s[t - d] : 0;
        __syncthreads();
        s[t] += u;
        __syncthreads();
    }
    if (t < NBLK_A) partial[sb * NBLK_A + t] = s[t] - v;   // exclusive
    if (t == 255) total[sb] = s[255];
}

// scan of superbucket totals -> bbase; threads <128 also prep W2 fragments
__global__ __launch_bounds__(512) void k_scanB_w2(
    const int* __restrict__ total, int* __restrict__ bbase,
    const float* __restrict__ W2, __bf16* __restrict__ w2hi, __bf16* __restrict__ w2lo)
{
    __shared__ int s[512];
    int t = threadIdx.x;
    int v = (t < NSB) ? total[t] : 0;
    s[t] = v;
    __syncthreads();
    #pragma unroll
    for (int d = 1; d < 512; d <<= 1){
        int u = (t >= d) ? s[t - d] : 0;
        __syncthreads();
        s[t] += u;
        __syncthreads();
    }
    if (t < NSB) bbase[t] = s[t] - v;
    if (t < 128){
        int h = t >> 6, l = t & 63;
        bf16x8 vh, vl;
        #pragma unroll
        for (int j = 0; j < 8; j++){
            float w = W2[((l >> 4) * 8 + j) * 32 + h * 16 + (l & 15)];
            __bf16 hi = (__bf16)w;
            vh[j] = hi;
            vl[j] = (__bf16)(w - (float)hi);
        }
        ((bf16x8*)w2hi)[t] = vh;
        ((bf16x8*)w2lo)[t] = vl;
    }
}

// phase A3: single-writer runs per (block,superbucket); LDS atomics only
__global__ __launch_bounds__(256) void k_sbscatter(
    const int* __restrict__ eC, const int* __restrict__ eV,
    const int* __restrict__ partial, const int* __restrict__ bbase,
    unsigned* __restrict__ pbuf)
{
    __shared__ int lcur[NSB];
    int t = threadIdx.x, blk = blockIdx.x;
    for (int i = t; i < NSB; i += 256) lcur[i] = bbase[i] + partial[i * NBLK_A + blk];
    __syncthreads();
    int base = blk * EPB;
    for (int i = base + t; i < base + EPB; i += 256){
        int kc = eC[i], kv = eV[i];
        int p1 = atomicAdd(&lcur[kc >> 9], 1);
        pbuf[p1] = ((unsigned)(kc & 511) << 17) | (unsigned)kv;
        int gk = NC_N + kv;
        int p2 = atomicAdd(&lcur[gk >> 9], 1);
        pbuf[p2] = ((unsigned)(gk & 511) << 17) | (unsigned)kc;
    }
}

// phase B: one block per superbucket; 512-bin hist/scan -> cnt/offs; LDS-staged
// permute; fully COALESCED elist write.
__global__ __launch_bounds__(256) void k_sbsort(
    const unsigned* __restrict__ pbuf, const int* __restrict__ bbase,
    const int* __restrict__ total, int* __restrict__ cnt,
    int* __restrict__ offs, int* __restrict__ elist)
{
    __shared__ int sout[SCAP];
    __shared__ int hist[SBK];
    __shared__ int cur[SBK];
    __shared__ int ts[256];
    int b = blockIdx.x, t = threadIdx.x;
    int base = bbase[b], n = total[b];
    if (n > SCAP) n = SCAP;             // safety clamp (never hit for this input)
    for (int i = t; i < SBK; i += 256) hist[i] = 0;
    __syncthreads();
    for (int i = t; i < n; i += 256) atomicAdd(&hist[pbuf[base + i] >> 17], 1);
    __syncthreads();
    int h0 = hist[2*t], h1 = hist[2*t+1];
    int tsum = h0 + h1;
    ts[t] = tsum;
    __syncthreads();
    #pragma unroll
    for (int d = 1; d < 256; d <<= 1){
        int u = (t >= d) ? ts[t - d] : 0;
        __syncthreads();
        ts[t] += u;
        __syncthreads();
    }
    int e0 = ts[t] - tsum;
    int e1 = e0 + h0;
    cur[2*t]   = e0;                    // LOCAL offsets into sout
    cur[2*t+1] = e1;
    int g = b * SBK + 2*t;
    if (g   < NKEY){ cnt[g]   = h0; offs[g]   = base + e0; }
    if (g+1 < NKEY){ cnt[g+1] = h1; offs[g+1] = base + e1; }
    __syncthreads();
    for (int i = t; i < n; i += 256){
        unsigned p = pbuf[base + i];
        int pos = atomicAdd(&cur[p >> 17], 1);
        sout[pos] = (int)(p & 0x1FFFFu);
    }
    __syncthreads();
    for (int i = t; i < n; i += 256) elist[base + i] = sout[i];
}

// ---------------- MFMA edge pass: one wave per target node -------------------
// h_e = relu(Pconst[node] + b1 + Pvar[other_e])  (P tables fp16, math f32)
// G = H @ W2 via hi/lo bf16 MFMA; acc[node][col] = sum_e relu(G[e][col]+b2[col]).
__global__ __launch_bounds__(256) void k_edge_mfma(
    const _Float16* __restrict__ Pconst, const _Float16* __restrict__ Pvar,
    const int* __restrict__ offs, const int* __restrict__ cnt,
    const int* __restrict__ elist,
    const __bf16* __restrict__ w2hi, const __bf16* __restrict__ w2lo,
    const float* __restrict__ b1, const float* __restrict__ b2,
    float* __restrict__ accum, int n)
{
    int wid = (blockIdx.x * 256 + threadIdx.x) >> 6;
    int l   = threadIdx.x & 63;
    if (wid >= n) return;
    int row = l & 15;     // A-row (edge within tile) / C-col
    int kg  = l >> 4;     // k-chunk group

    bf16x8 wh0 = ((const bf16x8*)w2hi)[l];
    bf16x8 wh1 = ((const bf16x8*)w2hi)[64 + l];
    bf16x8 wl0 = ((const bf16x8*)w2lo)[l];
    bf16x8 wl1 = ((const bf16x8*)w2lo)[64 + l];
    float b2a = b2[row];
    float b2b = b2[16 + row];

    f16x8 pcv = *(const f16x8*)(Pconst + (size_t)wid * 32 + kg * 8);
    const float* pb = b1 + kg * 8;
    f32x4 pc0, pc1;
    #pragma unroll
    for (int j = 0; j < 4; j++){
        pc0[j] = (float)pcv[j]     + pb[j];
        pc1[j] = (float)pcv[4 + j] + pb[4 + j];
    }

    int start = offs[wid], deg = cnt[wid];
    float acc0 = 0.f, acc1 = 0.f;
    int ntile = (deg + 15) >> 4;

    for (int t = 0; t < ntile; t++){
        int r  = t * 16 + row;
        int rc = (r < deg) ? r : (deg - 1);
        int other = elist[start + rc];
        f16x8 av = *(const f16x8*)(Pvar + (size_t)other * 32 + kg * 8);

        bf16x8 ahi, alo;
        #pragma unroll
        for (int j = 0; j < 4; j++){
            float h0 = fmaxf(pc0[j] + (float)av[j],     0.f);
            float h1 = fmaxf(pc1[j] + (float)av[4 + j], 0.f);
            __bf16 H0 = (__bf16)h0;
            __bf16 H1 = (__bf16)h1;
            ahi[j]     = H0;  alo[j]     = (__bf16)(h0 - (float)H0);
            ahi[4 + j] = H1;  alo[4 + j] = (__bf16)(h1 - (float)H1);
        }

        f32x4 c0 = {0.f, 0.f, 0.f, 0.f}, c1 = {0.f, 0.f, 0.f, 0.f};
        c0 = __builtin_amdgcn_mfma_f32_16x16x32_bf16(ahi, wh0, c0, 0, 0, 0);
        c0 = __builtin_amdgcn_mfma_f32_16x16x32_bf16(ahi, wl0, c0, 0, 0, 0);
        c0 = __builtin_amdgcn_mfma_f32_16x16x32_bf16(alo, wh0, c0, 0, 0, 0);
        c1 = __builtin_amdgcn_mfma_f32_16x16x32_bf16(ahi, wh1, c1, 0, 0, 0);
        c1 = __builtin_amdgcn_mfma_f32_16x16x32_bf16(ahi, wl1, c1, 0, 0, 0);
        c1 = __builtin_amdgcn_mfma_f32_16x16x32_bf16(alo, wh1, c1, 0, 0, 0);

        #pragma unroll
        for (int rr = 0; rr < 4; rr++){
            int er = t * 16 + kg * 4 + rr;   // C row = edge index
            if (er < deg){
                acc0 += fmaxf(c0[rr] + b2a, 0.f);
                acc1 += fmaxf(c1[rr] + b2b, 0.f);
            }
        }
    }

    acc0 += __shfl_xor(acc0, 16, 64);
    acc0 += __shfl_xor(acc0, 32, 64);
    acc1 += __shfl_xor(acc1, 16, 64);
    acc1 += __shfl_xor(acc1, 32, 64);

    if (l < 16)      accum[(size_t)wid * 32 + l] = acc0;       // cols 0..15
    else if (l < 32) accum[(size_t)wid * 32 + l] = acc1;       // cols 16..31
}

// ---------------- fused representation / output ----------------

// out_c = relu(concat(acc, c) @ Wcr + bcr) -> cemb (in place) AND P = out_c @ W1c (fp16)
__global__ __launch_bounds__(256) void k_consrep_f(
    const float* __restrict__ acc, float* __restrict__ cemb,
    const float* __restrict__ Wcr, const float* __restrict__ bcr,
    const float* __restrict__ W1c, _Float16* __restrict__ P)
{
    int n = blockIdx.x * blockDim.x + threadIdx.x;
    if (n >= NC_N) return;
    float h[32];
    #pragma unroll
    for (int o = 0; o < 32; o++) h[o] = bcr[o];
    const float4* ap = (const float4*)(acc + (size_t)n * 32);
    #pragma unroll
    for (int q = 0; q < 8; q++){
        float4 t = ap[q];
        #pragma unroll
        for (int j = 0; j < 4; j++){
            float xk = (&t.x)[j];
            const float* w = Wcr + (q*4 + j)*32;
            #pragma unroll
            for (int o = 0; o < 32; o++) h[o] = fmaf(xk, w[o], h[o]);
        }
    }
    const float4* cp = (const float4*)(cemb + (size_t)n * 32);
    #pragma unroll
    for (int q = 0; q < 8; q++){
        float4 t = cp[q];
        #pragma unroll
        for (int j = 0; j < 4; j++){
            float xk = (&t.x)[j];
            const float* w = Wcr + (32 + q*4 + j)*32;
            #pragma unroll
            for (int o = 0; o < 32; o++) h[o] = fmaf(xk, w[o], h[o]);
        }
    }
    #pragma unroll
    for (int o = 0; o < 32; o++) h[o] = fmaxf(h[o], 0.f);
    float4* dst = (float4*)(cemb + (size_t)n * 32);
    #pragma unroll
    for (int q = 0; q < 8; q++){
        float4 r;
        #pragma unroll
        for (int j = 0; j < 4; j++) (&r.x)[j] = h[q*4 + j];
        dst[q] = r;
    }
    float p[32];
    #pragma unroll
    for (int o = 0; o < 32; o++) p[o] = 0.f;
    #pragma unroll
    for (int k = 0; k < 32; k++){
        float hk = h[k];
        const float* w = W1c + k*32;
        #pragma unroll
        for (int o = 0; o < 32; o++) p[o] = fmaf(hk, w[o], p[o]);
    }
    f16x8* dp = (f16x8*)(P + (size_t)n * 32);
    #pragma unroll
    for (int q = 0; q < 4; q++){
        f16x8 r;
        #pragma unroll
        for (int j = 0; j < 8; j++) r[j] = (_Float16)p[q*8 + j];
        dp[q] = r;
    }
}

__global__ __launch_bounds__(256) void k_out(
    const float* __restrict__ acc, const float* __restrict__ vemb,
    const float* __restrict__ Wvr, const float* __restrict__ bvr,
    const float* __restrict__ Wo1, const float* __restrict__ bo1,
    const float* __restrict__ Wo2, const float* __restrict__ bo2,
    const float* __restrict__ Wo3, const float* __restrict__ bo3,
    float* __restrict__ out)
{
    int n = blockIdx.x * blockDim.x + threadIdx.x;
    if (n >= NV_N) return;
    float a[32];
    #pragma unroll
    for (int o = 0; o < 32; o++) a[o] = bvr[o];
    const float4* ap = (const float4*)(acc + (size_t)n * 32);
    #pragma unroll
    for (int q = 0; q < 8; q++){
        float4 t = ap[q];
        #pragma unroll
        for (int j = 0; j < 4; j++){
            float xk = (&t.x)[j];
            const float* w = Wvr + (q*4 + j)*32;
            #pragma unroll
            for (int o = 0; o < 32; o++) a[o] = fmaf(xk, w[o], a[o]);
        }
    }
    const float4* vp = (const float4*)(vemb + (size_t)n * 32);
    #pragma unroll
    for (int q = 0; q < 8; q++){
        float4 t = vp[q];
        #pragma unroll
        for (int j = 0; j < 4; j++){
            float xk = (&t.x)[j];
            const float* w = Wvr + (32 + q*4 + j)*32;
            #pragma unroll
            for (int o = 0; o < 32; o++) a[o] = fmaf(xk, w[o], a[o]);
        }
    }
    #pragma unroll
    for (int o = 0; o < 32; o++) a[o] = fmaxf(a[o], 0.f);

    float c[32];
    #pragma unroll
    for (int o = 0; o < 32; o++) c[o] = bo1[o];
    #pragma unroll
    for (int k = 0; k < 32; k++){
        float ak = a[k];
        const float* w = Wo1 + k*32;
        #pragma unroll
        for (int o = 0; o < 32; o++) c[o] = fmaf(ak, w[o], c[o]);
    }
    #pragma unroll
    for (int o = 0; o < 32; o++) c[o] = fmaxf(c[o], 0.f);

    float d[32];
    #pragma unroll
    for (int o = 0; o < 32; o++) d[o] = bo2[o];
    #pragma unroll
    for (int k = 0; k < 32; k++){
        float ck = c[k];
        const float* w = Wo2 + k*32;
        #pragma unroll
        for (int o = 0; o < 32; o++) d[o] = fmaf(ck, w[o], d[o]);
    }
    float s = bo3[0];
    #pragma unroll
    for (int k = 0; k < 32; k++) s = fmaf(fmaxf(d[k], 0.f), Wo3[k], s);
    out[n] = s;
}

// ---------------- launch ----------------

extern "C" void kernel_launch(void* const* d_in, const int* in_sizes, int n_in,
                              void* d_out, int out_size, void* d_ws, size_t ws_size,
                              hipStream_t stream)
{
    (void)in_sizes; (void)n_in; (void)out_size; (void)ws_size;
    const float* consF = (const float*)d_in[0];
    const float* varsF = (const float*)d_in[1];
    const int*   eidx  = (const int*)d_in[2];
    const int*   eCons = eidx;
    const int*   eVars = eidx + E_N;

    const float* Wc  = (const float*)d_in[3],  *bc  = (const float*)d_in[4];
    const float* Wv  = (const float*)d_in[5],  *bv  = (const float*)d_in[6];
    const float* Wj1 = (const float*)d_in[7],  *bj1 = (const float*)d_in[8];
    const float* Wj2 = (const float*)d_in[9],  *bj2 = (const float*)d_in[10];
    const float* Wcr = (const float*)d_in[11], *bcr = (const float*)d_in[12];
    const float* Wvr = (const float*)d_in[13], *bvr = (const float*)d_in[14];
    const float* Wo1 = (const float*)d_in[15], *bo1 = (const float*)d_in[16];
    const float* Wo2 = (const float*)d_in[17], *bo2 = (const float*)d_in[18];
    const float* Wo3 = (const float*)d_in[19], *bo3 = (const float*)d_in[20];

    const size_t NT = (size_t)100000 * 32;
    float*    c_emb = (float*)d_ws;             // 12.8 MB; -> out_c in place
    float*    v_emb = c_emb + NT;               // 12.8 MB
    _Float16* P1    = (_Float16*)(v_emb + NT);  // 6.4 MB fp16 (var pass1 / const pass2)
    _Float16* P2    = P1 + NT;                  // 6.4 MB fp16 (const pass1 / var pass2)
    float*    accum = (float*)(P2 + NT);        // 12.8 MB segment sums
    unsigned* pbuf  = (unsigned*)P1;            // overlay 25.6 MB over P1+P2+accum (dead during sort)
    int*   cnt     = (int*)(accum + NT);        // [NKEY]
    int*   offs    = cnt + NKEY;                // [NKEY]
    int*   hists   = offs + NKEY;               // [NSB*NBLK_A]
    int*   partial = hists + NSB*NBLK_A;        // [NSB*NBLK_A]
    int*   total   = partial + NSB*NBLK_A;      // [NSB]
    int*   bbase   = total + NSB;               // [NSB]
    int*   elist   = bbase + NSB;               // [2E]
    __bf16* w2hi   = (__bf16*)(elist + 2*E_N);  // [2][64][8]
    __bf16* w2lo   = w2hi + 1024;

    const float* W1c = Wj1;                     // rows 0..31  (cons/out_c side)
    const float* W1v = Wj1 + 32*32;             // rows 32..63 (vars side)

    // --- deterministic 3-phase counting sort for BOTH directions ---
    k_sbhist<<<dim3(NBLK_A), dim3(256), 0, stream>>>(eCons, eVars, hists);
    k_scanA<<<dim3(NSB), dim3(256), 0, stream>>>(hists, partial, total);
    k_scanB_w2<<<dim3(1), dim3(512), 0, stream>>>(total, bbase, Wj2, w2hi, w2lo);
    k_sbscatter<<<dim3(NBLK_A), dim3(256), 0, stream>>>(eCons, eVars, partial, bbase, pbuf);
    k_sbsort<<<dim3(NSB), dim3(256), 0, stream>>>(pbuf, bbase, total, cnt, offs, elist);

    // --- fused embeddings + layer-1 hoist (P1/P2 overwrite: pbuf is dead now) ---
    k_embed_cons_f<<<dim3(391), dim3(256), 0, stream>>>(consF, Wc, bc, W1c, c_emb, P2);
    k_embed_vars_f<<<dim3(391), dim3(256), 0, stream>>>(varsF, Wv, bv, W1v, v_emb, P1);

    // ---- pass 1: edges -> constraints (keys [0,NC)) ----
    k_edge_mfma<<<dim3(25000), dim3(256), 0, stream>>>(
        P2, P1, offs, cnt, elist, w2hi, w2lo, bj1, bj2, accum, NC_N);
    k_consrep_f<<<dim3(391), dim3(256), 0, stream>>>(accum, c_emb, Wcr, bcr, W1c, P2);

    // ---- pass 2: edges -> variables (keys [NC,NC+NV)) ----
    k_edge_mfma<<<dim3(25000), dim3(256), 0, stream>>>(
        P1, P2, offs + NC_N, cnt + NC_N, elist, w2hi, w2lo, bj1, bj2, accum, NV_N);
    k_out<<<dim3(391), dim3(256), 0, stream>>>(accum, v_emb, Wvr, bvr,
                                               Wo1, bo1, Wo2, bo2, Wo3, bo3,
                                               (float*)d_out);
}

// Round 9
// 322.107 us; speedup vs baseline: 6.2306x; 1.0960x over previous
//
#include <hip/hip_runtime.h>

#define NC_N 100000
#define NV_N 100000
#define E_N  3200000
#define NKEY 200000          // unified key space: [0,NC) cons, [NC,NC+NV) vars
#define SBK  512             // keys per superbucket
#define NSB  391             // ceil(200000/512)
#define SCAP 18432           // per-superbucket capacity (mean 16368, sigma ~128)
#define NBLK_A 200
#define EPB  16000           // edges per phase-A block (200*16000 = E)

typedef __attribute__((ext_vector_type(8))) _Float16  f16x8;
typedef __attribute__((ext_vector_type(4))) float     f32x4;

// ---------------- fused node embedding kernels ----------------

// c = relu(cons_features @ Wc + bc); write c_emb (f32) AND P = c @ W1c (fp16)
__global__ __launch_bounds__(256) void k_embed_cons_f(
    const float* __restrict__ f, const float* __restrict__ Wc,
    const float* __restrict__ bc, const float* __restrict__ W1c,
    float* __restrict__ c_emb, _Float16* __restrict__ P)
{
    int n = blockIdx.x * blockDim.x + threadIdx.x;
    if (n >= NC_N) return;
    float f0 = f[2*(size_t)n], f1 = f[2*(size_t)n + 1];
    float c[32];
    #pragma unroll
    for (int o = 0; o < 32; o++)
        c[o] = fmaxf(fmaf(f0, Wc[o], fmaf(f1, Wc[32 + o], bc[o])), 0.f);
    float4* dc = (float4*)(c_emb + (size_t)n * 32);
    #pragma unroll
    for (int q = 0; q < 8; q++){
        float4 r;
        #pragma unroll
        for (int j = 0; j < 4; j++) (&r.x)[j] = c[q*4 + j];
        dc[q] = r;
    }
    float p[32];
    #pragma unroll
    for (int o = 0; o < 32; o++) p[o] = 0.f;
    #pragma unroll
    for (int k = 0; k < 32; k++){
        float ck = c[k];
        const float* w = W1c + k*32;
        #pragma unroll
        for (int o = 0; o < 32; o++) p[o] = fmaf(ck, w[o], p[o]);
    }
    f16x8* dp = (f16x8*)(P + (size_t)n * 32);
    #pragma unroll
    for (int q = 0; q < 4; q++){
        f16x8 r;
        #pragma unroll
        for (int j = 0; j < 8; j++) r[j] = (_Float16)p[q*8 + j];
        dp[q] = r;
    }
}

// v = relu(vars_features @ Wv + bv); write v_emb (f32) AND P = v @ W1v (fp16)
__global__ __launch_bounds__(256) void k_embed_vars_f(
    const float* __restrict__ f, const float* __restrict__ Wv,
    const float* __restrict__ bv, const float* __restrict__ W1v,
    float* __restrict__ v_emb, _Float16* __restrict__ P)
{
    int n = blockIdx.x * blockDim.x + threadIdx.x;
    if (n >= NV_N) return;
    float x[9];
    #pragma unroll
    for (int k = 0; k < 9; k++) x[k] = f[9*(size_t)n + k];
    float v[32];
    #pragma unroll
    for (int o = 0; o < 32; o++){
        float s = bv[o];
        #pragma unroll
        for (int k = 0; k < 9; k++) s = fmaf(x[k], Wv[k*32 + o], s);
        v[o] = fmaxf(s, 0.f);
    }
    float4* dv = (float4*)(v_emb + (size_t)n * 32);
    #pragma unroll
    for (int q = 0; q < 8; q++){
        float4 r;
        #pragma unroll
        for (int j = 0; j < 4; j++) (&r.x)[j] = v[q*4 + j];
        dv[q] = r;
    }
    float p[32];
    #pragma unroll
    for (int o = 0; o < 32; o++) p[o] = 0.f;
    #pragma unroll
    for (int k = 0; k < 32; k++){
        float vk = v[k];
        const float* w = W1v + k*32;
        #pragma unroll
        for (int o = 0; o < 32; o++) p[o] = fmaf(vk, w[o], p[o]);
    }
    f16x8* dp = (f16x8*)(P + (size_t)n * 32);
    #pragma unroll
    for (int q = 0; q < 4; q++){
        f16x8 r;
        #pragma unroll
        for (int j = 0; j < 8; j++) r[j] = (_Float16)p[q*8 + j];
        dp[q] = r;
    }
}

// ---------------- deterministic 3-phase counting sort ----------------

__global__ __launch_bounds__(256) void k_sbhist(
    const int* __restrict__ eC, const int* __restrict__ eV, int* __restrict__ hists)
{
    __shared__ int lh[NSB];
    int t = threadIdx.x, blk = blockIdx.x;
    for (int i = t; i < NSB; i += 256) lh[i] = 0;
    __syncthreads();
    int base = blk * EPB;
    for (int i = base + t; i < base + EPB; i += 256){
        int kc = eC[i], kv = eV[i];
        atomicAdd(&lh[kc >> 9], 1);
        atomicAdd(&lh[(NC_N + kv) >> 9], 1);
    }
    __syncthreads();
    for (int i = t; i < NSB; i += 256) hists[i * NBLK_A + blk] = lh[i];
}

__global__ __launch_bounds__(256) void k_scanA(
    const int* __restrict__ hists, int* __restrict__ partial, int* __restrict__ total)
{
    __shared__ int s[256];
    int sb = blockIdx.x, t = threadIdx.x;
    int v = (t < NBLK_A) ? hists[sb * NBLK_A + t] : 0;
    s[t] = v;
    __syncthreads();
    #pragma unroll
    for (int d = 1; d < 256; d <<= 1){
        int u = (t >= d) ? s[t - d] : 0;
        __syncthreads();
        s[t] += u;
        __syncthreads();
    }
    if (t < NBLK_A) partial[sb * NBLK_A + t] = s[t] - v;   // exclusive
    if (t == 255) total[sb] = s[255];
}

// scan of superbucket totals -> bbase; threads <128 also prep W2 fp16 hi/lo frags
__global__ __launch_bounds__(512) void k_scanB_w2(
    const int* __restrict__ total, int* __restrict__ bbase,
    const float* __restrict__ W2, _Float16* __restrict__ w2hi, _Float16* __restrict__ w2lo)
{
    __shared__ int s[512];
    int t = threadIdx.x;
    int v = (t < NSB) ? total[t] : 0;
    s[t] = v;
    __syncthreads();
    #pragma unroll
    for (int d = 1; d < 512; d <<= 1){
        int u = (t >= d) ? s[t - d] : 0;
        __syncthreads();
        s[t] += u;
        __syncthreads();
    }
    if (t < NSB) bbase[t] = s[t] - v;
    if (t < 128){
        int h = t >> 6, l = t & 63;
        f16x8 vh, vl;
        #pragma unroll
        for (int j = 0; j < 8; j++){
            float w = W2[((l >> 4) * 8 + j) * 32 + h * 16 + (l & 15)];
            _Float16 hi = (_Float16)w;
            vh[j] = hi;
            vl[j] = (_Float16)(w - (float)hi);
        }
        ((f16x8*)w2hi)[t] = vh;
        ((f16x8*)w2lo)[t] = vl;
    }
}

// phase A3: single-writer runs per (block,superbucket); LDS atomics only
__global__ __launch_bounds__(256) void k_sbscatter(
    const int* __restrict__ eC, const int* __restrict__ eV,
    const int* __restrict__ partial, const int* __restrict__ bbase,
    unsigned* __restrict__ pbuf)
{
    __shared__ int lcur[NSB];
    int t = threadIdx.x, blk = blockIdx.x;
    for (int i = t; i < NSB; i += 256) lcur[i] = bbase[i] + partial[i * NBLK_A + blk];
    __syncthreads();
    int base = blk * EPB;
    for (int i = base + t; i < base + EPB; i += 256){
        int kc = eC[i], kv = eV[i];
        int p1 = atomicAdd(&lcur[kc >> 9], 1);
        pbuf[p1] = ((unsigned)(kc & 511) << 17) | (unsigned)kv;
        int gk = NC_N + kv;
        int p2 = atomicAdd(&lcur[gk >> 9], 1);
        pbuf[p2] = ((unsigned)(gk & 511) << 17) | (unsigned)kc;
    }
}

// phase B: one block per superbucket; 512-bin hist/scan -> cnt/offs; LDS-staged
// permute; fully COALESCED elist write.
__global__ __launch_bounds__(256) void k_sbsort(
    const unsigned* __restrict__ pbuf, const int* __restrict__ bbase,
    const int* __restrict__ total, int* __restrict__ cnt,
    int* __restrict__ offs, int* __restrict__ elist)
{
    __shared__ int sout[SCAP];
    __shared__ int hist[SBK];
    __shared__ int cur[SBK];
    __shared__ int ts[256];
    int b = blockIdx.x, t = threadIdx.x;
    int base = bbase[b], n = total[b];
    if (n > SCAP) n = SCAP;             // safety clamp (never hit for this input)
    for (int i = t; i < SBK; i += 256) hist[i] = 0;
    __syncthreads();
    for (int i = t; i < n; i += 256) atomicAdd(&hist[pbuf[base + i] >> 17], 1);
    __syncthreads();
    int h0 = hist[2*t], h1 = hist[2*t+1];
    int tsum = h0 + h1;
    ts[t] = tsum;
    __syncthreads();
    #pragma unroll
    for (int d = 1; d < 256; d <<= 1){
        int u = (t >= d) ? ts[t - d] : 0;
        __syncthreads();
        ts[t] += u;
        __syncthreads();
    }
    int e0 = ts[t] - tsum;
    int e1 = e0 + h0;
    cur[2*t]   = e0;                    // LOCAL offsets into sout
    cur[2*t+1] = e1;
    int g = b * SBK + 2*t;
    if (g   < NKEY){ cnt[g]   = h0; offs[g]   = base + e0; }
    if (g+1 < NKEY){ cnt[g+1] = h1; offs[g+1] = base + e1; }
    __syncthreads();
    for (int i = t; i < n; i += 256){
        unsigned p = pbuf[base + i];
        int pos = atomicAdd(&cur[p >> 17], 1);
        sout[pos] = (int)(p & 0x1FFFFu);
    }
    __syncthreads();
    for (int i = t; i < n; i += 256) elist[base + i] = sout[i];
}

// ---------------- MFMA edge pass: one wave per target node -------------------
// h_e = relu(pc16 + Pvar[other_e]) in PACKED fp16; G = H @ W2 via f16 MFMA with
// fp16 hi/lo weight split; acc[node][col] = sum_e relu(G[e][col] + b2[col]).
__global__ __launch_bounds__(256) void k_edge_mfma(
    const _Float16* __restrict__ Pconst, const _Float16* __restrict__ Pvar,
    const int* __restrict__ offs, const int* __restrict__ cnt,
    const int* __restrict__ elist,
    const _Float16* __restrict__ w2hi, const _Float16* __restrict__ w2lo,
    const float* __restrict__ b1, const float* __restrict__ b2,
    float* __restrict__ accum, int n)
{
    int wid = (blockIdx.x * 256 + threadIdx.x) >> 6;
    int l   = threadIdx.x & 63;
    if (wid >= n) return;
    int row = l & 15;     // A-row (edge within tile) / C-col
    int kg  = l >> 4;     // k-chunk group

    f16x8 wh0 = ((const f16x8*)w2hi)[l];
    f16x8 wh1 = ((const f16x8*)w2hi)[64 + l];
    f16x8 wl0 = ((const f16x8*)w2lo)[l];
    f16x8 wl1 = ((const f16x8*)w2lo)[64 + l];
    float b2a = b2[row];
    float b2b = b2[16 + row];

    // pc16 = fp16(Pconst_row + b1), packed once per wave
    f16x8 pcv = *(const f16x8*)(Pconst + (size_t)wid * 32 + kg * 8);
    const float* pb = b1 + kg * 8;
    f16x8 pc16;
    #pragma unroll
    for (int j = 0; j < 8; j++) pc16[j] = (_Float16)((float)pcv[j] + pb[j]);
    const f16x8 zero = {};

    int start = offs[wid], deg = cnt[wid];
    float acc0 = 0.f, acc1 = 0.f;
    int nfull = deg >> 4;

    for (int t = 0; t < nfull; t++){
        int other = elist[start + t * 16 + row];
        f16x8 av = *(const f16x8*)(Pvar + (size_t)other * 32 + kg * 8);
        f16x8 h = __builtin_elementwise_max(av + pc16, zero);   // v_pk_add/max_f16

        f32x4 c0 = {0.f, 0.f, 0.f, 0.f}, c1 = {0.f, 0.f, 0.f, 0.f};
        c0 = __builtin_amdgcn_mfma_f32_16x16x32_f16(h, wh0, c0, 0, 0, 0);
        c0 = __builtin_amdgcn_mfma_f32_16x16x32_f16(h, wl0, c0, 0, 0, 0);
        c1 = __builtin_amdgcn_mfma_f32_16x16x32_f16(h, wh1, c1, 0, 0, 0);
        c1 = __builtin_amdgcn_mfma_f32_16x16x32_f16(h, wl1, c1, 0, 0, 0);

        #pragma unroll
        for (int rr = 0; rr < 4; rr++){
            acc0 += fmaxf(c0[rr] + b2a, 0.f);
            acc1 += fmaxf(c1[rr] + b2b, 0.f);
        }
    }
    if (deg & 15){                       // predicated tail tile
        int r  = nfull * 16 + row;
        int rc = (r < deg) ? r : (deg - 1);
        int other = elist[start + rc];
        f16x8 av = *(const f16x8*)(Pvar + (size_t)other * 32 + kg * 8);
        f16x8 h = __builtin_elementwise_max(av + pc16, zero);

        f32x4 c0 = {0.f, 0.f, 0.f, 0.f}, c1 = {0.f, 0.f, 0.f, 0.f};
        c0 = __builtin_amdgcn_mfma_f32_16x16x32_f16(h, wh0, c0, 0, 0, 0);
        c0 = __builtin_amdgcn_mfma_f32_16x16x32_f16(h, wl0, c0, 0, 0, 0);
        c1 = __builtin_amdgcn_mfma_f32_16x16x32_f16(h, wh1, c1, 0, 0, 0);
        c1 = __builtin_amdgcn_mfma_f32_16x16x32_f16(h, wl1, c1, 0, 0, 0);

        #pragma unroll
        for (int rr = 0; rr < 4; rr++){
            int er = nfull * 16 + kg * 4 + rr;   // C row = edge index
            if (er < deg){
                acc0 += fmaxf(c0[rr] + b2a, 0.f);
                acc1 += fmaxf(c1[rr] + b2b, 0.f);
            }
        }
    }

    acc0 += __shfl_xor(acc0, 16, 64);
    acc0 += __shfl_xor(acc0, 32, 64);
    acc1 += __shfl_xor(acc1, 16, 64);
    acc1 += __shfl_xor(acc1, 32, 64);

    if (l < 16)      accum[(size_t)wid * 32 + l] = acc0;       // cols 0..15
    else if (l < 32) accum[(size_t)wid * 32 + l] = acc1;       // cols 16..31
}

// ---------------- fused representation / output ----------------

// out_c = relu(concat(acc, c) @ Wcr + bcr) -> cemb (in place) AND P = out_c @ W1c (fp16)
__global__ __launch_bounds__(256) void k_consrep_f(
    const float* __restrict__ acc, float* __restrict__ cemb,
    const float* __restrict__ Wcr, const float* __restrict__ bcr,
    const float* __restrict__ W1c, _Float16* __restrict__ P)
{
    int n = blockIdx.x * blockDim.x + threadIdx.x;
    if (n >= NC_N) return;
    float h[32];
    #pragma unroll
    for (int o = 0; o < 32; o++) h[o] = bcr[o];
    const float4* ap = (const float4*)(acc + (size_t)n * 32);
    #pragma unroll
    for (int q = 0; q < 8; q++){
        float4 t = ap[q];
        #pragma unroll
        for (int j = 0; j < 4; j++){
            float xk = (&t.x)[j];
            const float* w = Wcr + (q*4 + j)*32;
            #pragma unroll
            for (int o = 0; o < 32; o++) h[o] = fmaf(xk, w[o], h[o]);
        }
    }
    const float4* cp = (const float4*)(cemb + (size_t)n * 32);
    #pragma unroll
    for (int q = 0; q < 8; q++){
        float4 t = cp[q];
        #pragma unroll
        for (int j = 0; j < 4; j++){
            float xk = (&t.x)[j];
            const float* w = Wcr + (32 + q*4 + j)*32;
            #pragma unroll
            for (int o = 0; o < 32; o++) h[o] = fmaf(xk, w[o], h[o]);
        }
    }
    #pragma unroll
    for (int o = 0; o < 32; o++) h[o] = fmaxf(h[o], 0.f);
    float4* dst = (float4*)(cemb + (size_t)n * 32);
    #pragma unroll
    for (int q = 0; q < 8; q++){
        float4 r;
        #pragma unroll
        for (int j = 0; j < 4; j++) (&r.x)[j] = h[q*4 + j];
        dst[q] = r;
    }
    float p[32];
    #pragma unroll
    for (int o = 0; o < 32; o++) p[o] = 0.f;
    #pragma unroll
    for (int k = 0; k < 32; k++){
        float hk = h[k];
        const float* w = W1c + k*32;
        #pragma unroll
        for (int o = 0; o < 32; o++) p[o] = fmaf(hk, w[o], p[o]);
    }
    f16x8* dp = (f16x8*)(P + (size_t)n * 32);
    #pragma unroll
    for (int q = 0; q < 4; q++){
        f16x8 r;
        #pragma unroll
        for (int j = 0; j < 8; j++) r[j] = (_Float16)p[q*8 + j];
        dp[q] = r;
    }
}

__global__ __launch_bounds__(256) void k_out(
    const float* __restrict__ acc, const float* __restrict__ vemb,
    const float* __restrict__ Wvr, const float* __restrict__ bvr,
    const float* __restrict__ Wo1, const float* __restrict__ bo1,
    const float* __restrict__ Wo2, const float* __restrict__ bo2,
    const float* __restrict__ Wo3, const float* __restrict__ bo3,
    float* __restrict__ out)
{
    int n = blockIdx.x * blockDim.x + threadIdx.x;
    if (n >= NV_N) return;
    float a[32];
    #pragma unroll
    for (int o = 0; o < 32; o++) a[o] = bvr[o];
    const float4* ap = (const float4*)(acc + (size_t)n * 32);
    #pragma unroll
    for (int q = 0; q < 8; q++){
        float4 t = ap[q];
        #pragma unroll
        for (int j = 0; j < 4; j++){
            float xk = (&t.x)[j];
            const float* w = Wvr + (q*4 + j)*32;
            #pragma unroll
            for (int o = 0; o < 32; o++) a[o] = fmaf(xk, w[o], a[o]);
        }
    }
    const float4* vp = (const float4*)(vemb + (size_t)n * 32);
    #pragma unroll
    for (int q = 0; q < 8; q++){
        float4 t = vp[q];
        #pragma unroll
        for (int j = 0; j < 4; j++){
            float xk = (&t.x)[j];
            const float* w = Wvr + (32 + q*4 + j)*32;
            #pragma unroll
            for (int o = 0; o < 32; o++) a[o] = fmaf(xk, w[o], a[o]);
        }
    }
    #pragma unroll
    for (int o = 0; o < 32; o++) a[o] = fmaxf(a[o], 0.f);

    float c[32];
    #pragma unroll
    for (int o = 0; o < 32; o++) c[o] = bo1[o];
    #pragma unroll
    for (int k = 0; k < 32; k++){
        float ak = a[k];
        const float* w = Wo1 + k*32;
        #pragma unroll
        for (int o = 0; o < 32; o++) c[o] = fmaf(ak, w[o], c[o]);
    }
    #pragma unroll
    for (int o = 0; o < 32; o++) c[o] = fmaxf(c[o], 0.f);

    float d[32];
    #pragma unroll
    for (int o = 0; o < 32; o++) d[o] = bo2[o];
    #pragma unroll
    for (int k = 0; k < 32; k++){
        float ck = c[k];
        const float* w = Wo2 + k*32;
        #pragma unroll
        for (int o = 0; o < 32; o++) d[o] = fmaf(ck, w[o], d[o]);
    }
    float s = bo3[0];
    #pragma unroll
    for (int k = 0; k < 32; k++) s = fmaf(fmaxf(d[k], 0.f), Wo3[k], s);
    out[n] = s;
}

// ---------------- launch ----------------

extern "C" void kernel_launch(void* const* d_in, const int* in_sizes, int n_in,
                              void* d_out, int out_size, void* d_ws, size_t ws_size,
                              hipStream_t stream)
{
    (void)in_sizes; (void)n_in; (void)out_size; (void)ws_size;
    const float* consF = (const float*)d_in[0];
    const float* varsF = (const float*)d_in[1];
    const int*   eidx  = (const int*)d_in[2];
    const int*   eCons = eidx;
    const int*   eVars = eidx + E_N;

    const float* Wc  = (const float*)d_in[3],  *bc  = (const float*)d_in[4];
    const float* Wv  = (const float*)d_in[5],  *bv  = (const float*)d_in[6];
    const float* Wj1 = (const float*)d_in[7],  *bj1 = (const float*)d_in[8];
    const float* Wj2 = (const float*)d_in[9],  *bj2 = (const float*)d_in[10];
    const float* Wcr = (const float*)d_in[11], *bcr = (const float*)d_in[12];
    const float* Wvr = (const float*)d_in[13], *bvr = (const float*)d_in[14];
    const float* Wo1 = (const float*)d_in[15], *bo1 = (const float*)d_in[16];
    const float* Wo2 = (const float*)d_in[17], *bo2 = (const float*)d_in[18];
    const float* Wo3 = (const float*)d_in[19], *bo3 = (const float*)d_in[20];

    const size_t NT = (size_t)100000 * 32;
    float*    c_emb = (float*)d_ws;             // 12.8 MB; -> out_c in place
    float*    v_emb = c_emb + NT;               // 12.8 MB
    _Float16* P1    = (_Float16*)(v_emb + NT);  // 6.4 MB fp16 (var pass1 / const pass2)
    _Float16* P2    = P1 + NT;                  // 6.4 MB fp16 (const pass1 / var pass2)
    float*    accum = (float*)(P2 + NT);        // 12.8 MB segment sums
    unsigned* pbuf  = (unsigned*)P1;            // overlay 25.6 MB over P1+P2+accum (dead during sort)
    int*   cnt     = (int*)(accum + NT);        // [NKEY]
    int*   offs    = cnt + NKEY;                // [NKEY]
    int*   hists   = offs + NKEY;               // [NSB*NBLK_A]
    int*   partial = hists + NSB*NBLK_A;        // [NSB*NBLK_A]
    int*   total   = partial + NSB*NBLK_A;      // [NSB]
    int*   bbase   = total + NSB;               // [NSB]
    int*   elist   = bbase + NSB;               // [2E]
    _Float16* w2hi = (_Float16*)(elist + 2*E_N);// [2][64][8]
    _Float16* w2lo = w2hi + 1024;

    const float* W1c = Wj1;                     // rows 0..31  (cons/out_c side)
    const float* W1v = Wj1 + 32*32;             // rows 32..63 (vars side)

    // --- deterministic 3-phase counting sort for BOTH directions ---
    k_sbhist<<<dim3(NBLK_A), dim3(256), 0, stream>>>(eCons, eVars, hists);
    k_scanA<<<dim3(NSB), dim3(256), 0, stream>>>(hists, partial, total);
    k_scanB_w2<<<dim3(1), dim3(512), 0, stream>>>(total, bbase, Wj2, w2hi, w2lo);
    k_sbscatter<<<dim3(NBLK_A), dim3(256), 0, stream>>>(eCons, eVars, partial, bbase, pbuf);
    k_sbsort<<<dim3(NSB), dim3(256), 0, stream>>>(pbuf, bbase, total, cnt, offs, elist);

    // --- fused embeddings + layer-1 hoist (P1/P2 overwrite: pbuf is dead now) ---
    k_embed_cons_f<<<dim3(391), dim3(256), 0, stream>>>(consF, Wc, bc, W1c, c_emb, P2);
    k_embed_vars_f<<<dim3(391), dim3(256), 0, stream>>>(varsF, Wv, bv, W1v, v_emb, P1);

    // ---- pass 1: edges -> constraints (keys [0,NC)) ----
    k_edge_mfma<<<dim3(25000), dim3(256), 0, stream>>>(
        P2, P1, offs, cnt, elist, w2hi, w2lo, bj1, bj2, accum, NC_N);
    k_consrep_f<<<dim3(391), dim3(256), 0, stream>>>(accum, c_emb, Wcr, bcr, W1c, P2);

    // ---- pass 2: edges -> variables (keys [NC,NC+NV)) ----
    k_edge_mfma<<<dim3(25000), dim3(256), 0, stream>>>(
        P1, P2, offs + NC_N, cnt + NC_N, elist, w2hi, w2lo, bj1, bj2, accum, NV_N);
    k_out<<<dim3(391), dim3(256), 0, stream>>>(accum, v_emb, Wvr, bvr,
                                               Wo1, bo1, Wo2, bo2, Wo3, bo3,
                                               (float*)d_out);
}

// Round 10
// 298.632 us; speedup vs baseline: 6.7204x; 1.0786x over previous
//
#include <hip/hip_runtime.h>

#define NC_N 100000
#define NV_N 100000
#define E_N  3200000
#define NKEY 200000          // unified key space: [0,NC) cons, [NC,NC+NV) vars
#define SBK  512             // keys per superbucket
#define NSB  391             // ceil(200000/512)
#define SCAP 18432           // per-superbucket capacity (mean 16368, sigma ~128)
#define NBLK_A 400
#define EPB4 2000            // int4 quads per phase-A block (400*2000*4 = E)
#define PAD  (16*NSB)        // base-padding slack for pbuf/elist

typedef __attribute__((ext_vector_type(8))) _Float16  f16x8;
typedef __attribute__((ext_vector_type(4))) float     f32x4;

// ---------------- fused node embedding (cons + vars in one grid) ----------------

__global__ __launch_bounds__(256) void k_embed_all(
    const float* __restrict__ consF, const float* __restrict__ varsF,
    const float* __restrict__ Wc, const float* __restrict__ bc,
    const float* __restrict__ Wv, const float* __restrict__ bv,
    const float* __restrict__ W1c, const float* __restrict__ W1v,
    float* __restrict__ c_emb, float* __restrict__ v_emb,
    _Float16* __restrict__ Pc, _Float16* __restrict__ Pv)
{
    int n = blockIdx.x * blockDim.x + threadIdx.x;
    if (n < NC_N){
        float f0 = consF[2*(size_t)n], f1 = consF[2*(size_t)n + 1];
        float c[32];
        #pragma unroll
        for (int o = 0; o < 32; o++)
            c[o] = fmaxf(fmaf(f0, Wc[o], fmaf(f1, Wc[32 + o], bc[o])), 0.f);
        float4* dc = (float4*)(c_emb + (size_t)n * 32);
        #pragma unroll
        for (int q = 0; q < 8; q++){
            float4 r;
            #pragma unroll
            for (int j = 0; j < 4; j++) (&r.x)[j] = c[q*4 + j];
            dc[q] = r;
        }
        float p[32];
        #pragma unroll
        for (int o = 0; o < 32; o++) p[o] = 0.f;
        #pragma unroll
        for (int k = 0; k < 32; k++){
            float ck = c[k];
            const float* w = W1c + k*32;
            #pragma unroll
            for (int o = 0; o < 32; o++) p[o] = fmaf(ck, w[o], p[o]);
        }
        f16x8* dp = (f16x8*)(Pc + (size_t)n * 32);
        #pragma unroll
        for (int q = 0; q < 4; q++){
            f16x8 r;
            #pragma unroll
            for (int j = 0; j < 8; j++) r[j] = (_Float16)p[q*8 + j];
            dp[q] = r;
        }
    } else {
        int m = n - NC_N;
        if (m >= NV_N) return;
        float x[9];
        #pragma unroll
        for (int k = 0; k < 9; k++) x[k] = varsF[9*(size_t)m + k];
        float v[32];
        #pragma unroll
        for (int o = 0; o < 32; o++){
            float s = bv[o];
            #pragma unroll
            for (int k = 0; k < 9; k++) s = fmaf(x[k], Wv[k*32 + o], s);
            v[o] = fmaxf(s, 0.f);
        }
        float4* dv = (float4*)(v_emb + (size_t)m * 32);
        #pragma unroll
        for (int q = 0; q < 8; q++){
            float4 r;
            #pragma unroll
            for (int j = 0; j < 4; j++) (&r.x)[j] = v[q*4 + j];
            dv[q] = r;
        }
        float p[32];
        #pragma unroll
        for (int o = 0; o < 32; o++) p[o] = 0.f;
        #pragma unroll
        for (int k = 0; k < 32; k++){
            float vk = v[k];
            const float* w = W1v + k*32;
            #pragma unroll
            for (int o = 0; o < 32; o++) p[o] = fmaf(vk, w[o], p[o]);
        }
        f16x8* dp = (f16x8*)(Pv + (size_t)m * 32);
        #pragma unroll
        for (int q = 0; q < 4; q++){
            f16x8 r;
            #pragma unroll
            for (int j = 0; j < 8; j++) r[j] = (_Float16)p[q*8 + j];
            dp[q] = r;
        }
    }
}

// ---------------- deterministic 3-phase counting sort ----------------

__global__ __launch_bounds__(256) void k_sbhist(
    const int* __restrict__ eC, const int* __restrict__ eV, int* __restrict__ hists)
{
    __shared__ int lh[NSB];
    int t = threadIdx.x, blk = blockIdx.x;
    for (int i = t; i < NSB; i += 256) lh[i] = 0;
    __syncthreads();
    const int4* c4 = (const int4*)eC;
    const int4* v4 = (const int4*)eV;
    int qend = (blk + 1) * EPB4;
    for (int i = blk * EPB4 + t; i < qend; i += 256){
        int4 qc = c4[i];
        int4 qv = v4[i];
        #pragma unroll
        for (int j = 0; j < 4; j++){
            atomicAdd(&lh[(&qc.x)[j] >> 9], 1);
            atomicAdd(&lh[(NC_N + (&qv.x)[j]) >> 9], 1);
        }
    }
    __syncthreads();
    for (int i = t; i < NSB; i += 256) hists[i * NBLK_A + blk] = lh[i];
}

__global__ __launch_bounds__(512) void k_scanA(
    const int* __restrict__ hists, int* __restrict__ partial, int* __restrict__ total)
{
    __shared__ int s[512];
    int sb = blockIdx.x, t = threadIdx.x;
    int v = (t < NBLK_A) ? hists[sb * NBLK_A + t] : 0;
    s[t] = v;
    __syncthreads();
    #pragma unroll
    for (int d = 1; d < 512; d <<= 1){
        int u = (t >= d) ? s[t - d] : 0;
        __syncthreads();
        s[t] += u;
        __syncthreads();
    }
    if (t < NBLK_A) partial[sb * NBLK_A + t] = s[t] - v;   // exclusive
    if (t == 511) total[sb] = s[511];
}

// scan of PADDED superbucket totals -> 16-entry-aligned bbase; also W2 fp16 hi/lo prep
__global__ __launch_bounds__(512) void k_scanB_w2(
    const int* __restrict__ total, int* __restrict__ bbase,
    const float* __restrict__ W2, _Float16* __restrict__ w2hi, _Float16* __restrict__ w2lo)
{
    __shared__ int s[512];
    int t = threadIdx.x;
    int vp = (t < NSB) ? ((total[t] + 15) & ~15) : 0;
    s[t] = vp;
    __syncthreads();
    #pragma unroll
    for (int d = 1; d < 512; d <<= 1){
        int u = (t >= d) ? s[t - d] : 0;
        __syncthreads();
        s[t] += u;
        __syncthreads();
    }
    if (t < NSB) bbase[t] = s[t] - vp;
    if (t < 128){
        int h = t >> 6, l = t & 63;
        f16x8 vh, vl;
        #pragma unroll
        for (int j = 0; j < 8; j++){
            float w = W2[((l >> 4) * 8 + j) * 32 + h * 16 + (l & 15)];
            _Float16 hi = (_Float16)w;
            vh[j] = hi;
            vl[j] = (_Float16)(w - (float)hi);
        }
        ((f16x8*)w2hi)[t] = vh;
        ((f16x8*)w2lo)[t] = vl;
    }
}

// phase A3: single-writer runs per (block,superbucket); LDS atomics only
__global__ __launch_bounds__(256) void k_sbscatter(
    const int* __restrict__ eC, const int* __restrict__ eV,
    const int* __restrict__ partial, const int* __restrict__ bbase,
    unsigned* __restrict__ pbuf)
{
    __shared__ int lcur[NSB];
    int t = threadIdx.x, blk = blockIdx.x;
    for (int i = t; i < NSB; i += 256) lcur[i] = bbase[i] + partial[i * NBLK_A + blk];
    __syncthreads();
    const int4* c4 = (const int4*)eC;
    const int4* v4 = (const int4*)eV;
    int qend = (blk + 1) * EPB4;
    for (int i = blk * EPB4 + t; i < qend; i += 256){
        int4 qc = c4[i];
        int4 qv = v4[i];
        #pragma unroll
        for (int j = 0; j < 4; j++){
            int kc = (&qc.x)[j], kv = (&qv.x)[j];
            int p1 = atomicAdd(&lcur[kc >> 9], 1);
            pbuf[p1] = ((unsigned)(kc & 511) << 17) | (unsigned)kv;
            int gk = NC_N + kv;
            int p2 = atomicAdd(&lcur[gk >> 9], 1);
            pbuf[p2] = ((unsigned)(gk & 511) << 17) | (unsigned)kc;
        }
    }
}

// phase B: one block per superbucket; 512-bin hist/scan -> cnt/offs; LDS-staged
// permute; uint4 reads + int4 COALESCED elist write (bases 16-entry aligned).
__global__ __launch_bounds__(256) void k_sbsort(
    const unsigned* __restrict__ pbuf, const int* __restrict__ bbase,
    const int* __restrict__ total, int* __restrict__ cnt,
    int* __restrict__ offs, int* __restrict__ elist)
{
    __shared__ int sout[SCAP];
    __shared__ int hist[SBK];
    __shared__ int cur[SBK];
    __shared__ int ts[256];
    int b = blockIdx.x, t = threadIdx.x;
    int base = bbase[b], n = total[b];
    if (n > SCAP) n = SCAP;             // safety clamp (never hit for this input)
    int nq = n >> 2;
    const uint4* p4 = (const uint4*)(pbuf + base);
    for (int i = t; i < SBK; i += 256) hist[i] = 0;
    __syncthreads();
    for (int i = t; i < nq; i += 256){
        uint4 q = p4[i];
        atomicAdd(&hist[q.x >> 17], 1);
        atomicAdd(&hist[q.y >> 17], 1);
        atomicAdd(&hist[q.z >> 17], 1);
        atomicAdd(&hist[q.w >> 17], 1);
    }
    for (int i = (nq << 2) + t; i < n; i += 256) atomicAdd(&hist[pbuf[base + i] >> 17], 1);
    __syncthreads();
    int h0 = hist[2*t], h1 = hist[2*t+1];
    int tsum = h0 + h1;
    ts[t] = tsum;
    __syncthreads();
    #pragma unroll
    for (int d = 1; d < 256; d <<= 1){
        int u = (t >= d) ? ts[t - d] : 0;
        __syncthreads();
        ts[t] += u;
        __syncthreads();
    }
    int e0 = ts[t] - tsum;
    int e1 = e0 + h0;
    cur[2*t]   = e0;                    // LOCAL offsets into sout
    cur[2*t+1] = e1;
    int g = b * SBK + 2*t;
    if (g   < NKEY){ cnt[g]   = h0; offs[g]   = base + e0; }
    if (g+1 < NKEY){ cnt[g+1] = h1; offs[g+1] = base + e1; }
    __syncthreads();
    for (int i = t; i < nq; i += 256){
        uint4 q = p4[i];
        #pragma unroll
        for (int j = 0; j < 4; j++){
            unsigned p = (&q.x)[j];
            int pos = atomicAdd(&cur[p >> 17], 1);
            sout[pos] = (int)(p & 0x1FFFFu);
        }
    }
    for (int i = (nq << 2) + t; i < n; i += 256){
        unsigned p = pbuf[base + i];
        int pos = atomicAdd(&cur[p >> 17], 1);
        sout[pos] = (int)(p & 0x1FFFFu);
    }
    __syncthreads();
    int4* o4 = (int4*)(elist + base);
    for (int i = t; i < nq; i += 256){
        int4 w;
        w.x = sout[4*i]; w.y = sout[4*i+1]; w.z = sout[4*i+2]; w.w = sout[4*i+3];
        o4[i] = w;
    }
    for (int i = (nq << 2) + t; i < n; i += 256) elist[base + i] = sout[i];
}

// ---------------- MFMA edge pass: one wave per target node -------------------
// h_e = relu(pc16 + Pvar[other_e]) packed fp16; G = H @ W2 (f16 MFMA, hi/lo W);
// vector f32x4 epilogue; 32-bit saddr+voffset gathers.
__global__ __launch_bounds__(256) void k_edge_mfma(
    const _Float16* __restrict__ Pconst, const _Float16* __restrict__ Pvar,
    const int* __restrict__ offs, const int* __restrict__ cnt,
    const int* __restrict__ elist,
    const _Float16* __restrict__ w2hi, const _Float16* __restrict__ w2lo,
    const float* __restrict__ b1, const float* __restrict__ b2,
    float* __restrict__ accum, int n)
{
    int wid = (blockIdx.x * 256 + threadIdx.x) >> 6;
    int l   = threadIdx.x & 63;
    if (wid >= n) return;
    int row = l & 15;     // A-row (edge within tile) / C-col
    int kg  = l >> 4;     // k-chunk group

    f16x8 wh0 = ((const f16x8*)w2hi)[l];
    f16x8 wh1 = ((const f16x8*)w2hi)[64 + l];
    f16x8 wl0 = ((const f16x8*)w2lo)[l];
    f16x8 wl1 = ((const f16x8*)w2lo)[64 + l];
    float b2a = b2[row];
    float b2b = b2[16 + row];
    f32x4 vb2a = {b2a, b2a, b2a, b2a};
    f32x4 vb2b = {b2b, b2b, b2b, b2b};
    const f32x4 zf = {};
    const f16x8 zero = {};

    // pc16 = fp16(Pconst_row + b1), packed once per wave
    f16x8 pcv = *(const f16x8*)(Pconst + (size_t)wid * 32 + kg * 8);
    const float* pb = b1 + kg * 8;
    f16x8 pc16;
    #pragma unroll
    for (int j = 0; j < 8; j++) pc16[j] = (_Float16)((float)pcv[j] + pb[j]);

    int start = __builtin_amdgcn_readfirstlane(offs[wid]);
    int deg   = __builtin_amdgcn_readfirstlane(cnt[wid]);
    const int* el = elist + start;
    const char* pvb = (const char*)Pvar;
    unsigned kgo = (unsigned)(kg * 16);

    f32x4 a0v = {}, a1v = {};
    int nfull = deg >> 4;

    for (int t = 0; t < nfull; t++){
        unsigned other = (unsigned)el[t * 16 + row];
        f16x8 av = *(const f16x8*)(pvb + other * 64u + kgo);
        f16x8 h = __builtin_elementwise_max(av + pc16, zero);   // v_pk_add/max_f16

        f32x4 c0 = {}, c1 = {};
        c0 = __builtin_amdgcn_mfma_f32_16x16x32_f16(h, wh0, c0, 0, 0, 0);
        c0 = __builtin_amdgcn_mfma_f32_16x16x32_f16(h, wl0, c0, 0, 0, 0);
        c1 = __builtin_amdgcn_mfma_f32_16x16x32_f16(h, wh1, c1, 0, 0, 0);
        c1 = __builtin_amdgcn_mfma_f32_16x16x32_f16(h, wl1, c1, 0, 0, 0);

        a0v += __builtin_elementwise_max(c0 + vb2a, zf);        // v_pk_*_f32
        a1v += __builtin_elementwise_max(c1 + vb2b, zf);
    }
    if (deg & 15){                       // predicated tail tile
        int r  = nfull * 16 + row;
        int rc = (r < deg) ? r : (deg - 1);
        unsigned other = (unsigned)el[rc];
        f16x8 av = *(const f16x8*)(pvb + other * 64u + kgo);
        f16x8 h = __builtin_elementwise_max(av + pc16, zero);

        f32x4 c0 = {}, c1 = {};
        c0 = __builtin_amdgcn_mfma_f32_16x16x32_f16(h, wh0, c0, 0, 0, 0);
        c0 = __builtin_amdgcn_mfma_f32_16x16x32_f16(h, wl0, c0, 0, 0, 0);
        c1 = __builtin_amdgcn_mfma_f32_16x16x32_f16(h, wh1, c1, 0, 0, 0);
        c1 = __builtin_amdgcn_mfma_f32_16x16x32_f16(h, wl1, c1, 0, 0, 0);

        #pragma unroll
        for (int rr = 0; rr < 4; rr++){
            int er = nfull * 16 + kg * 4 + rr;   // C row = edge index
            if (er < deg){
                a0v[rr] += fmaxf(c0[rr] + b2a, 0.f);
                a1v[rr] += fmaxf(c1[rr] + b2b, 0.f);
            }
        }
    }

    float acc0 = (a0v[0] + a0v[1]) + (a0v[2] + a0v[3]);
    float acc1 = (a1v[0] + a1v[1]) + (a1v[2] + a1v[3]);
    acc0 += __shfl_xor(acc0, 16, 64);
    acc0 += __shfl_xor(acc0, 32, 64);
    acc1 += __shfl_xor(acc1, 16, 64);
    acc1 += __shfl_xor(acc1, 32, 64);

    if (l < 16)      accum[(size_t)wid * 32 + l] = acc0;       // cols 0..15
    else if (l < 32) accum[(size_t)wid * 32 + l] = acc1;       // cols 16..31
}

// ---------------- fused representation / output ----------------

// out_c = relu(concat(acc, c) @ Wcr + bcr) -> cemb (in place) AND P = out_c @ W1c (fp16)
__global__ __launch_bounds__(256) void k_consrep_f(
    const float* __restrict__ acc, float* __restrict__ cemb,
    const float* __restrict__ Wcr, const float* __restrict__ bcr,
    const float* __restrict__ W1c, _Float16* __restrict__ P)
{
    int n = blockIdx.x * blockDim.x + threadIdx.x;
    if (n >= NC_N) return;
    float h[32];
    #pragma unroll
    for (int o = 0; o < 32; o++) h[o] = bcr[o];
    const float4* ap = (const float4*)(acc + (size_t)n * 32);
    #pragma unroll
    for (int q = 0; q < 8; q++){
        float4 t = ap[q];
        #pragma unroll
        for (int j = 0; j < 4; j++){
            float xk = (&t.x)[j];
            const float* w = Wcr + (q*4 + j)*32;
            #pragma unroll
            for (int o = 0; o < 32; o++) h[o] = fmaf(xk, w[o], h[o]);
        }
    }
    const float4* cp = (const float4*)(cemb + (size_t)n * 32);
    #pragma unroll
    for (int q = 0; q < 8; q++){
        float4 t = cp[q];
        #pragma unroll
        for (int j = 0; j < 4; j++){
            float xk = (&t.x)[j];
            const float* w = Wcr + (32 + q*4 + j)*32;
            #pragma unroll
            for (int o = 0; o < 32; o++) h[o] = fmaf(xk, w[o], h[o]);
        }
    }
    #pragma unroll
    for (int o = 0; o < 32; o++) h[o] = fmaxf(h[o], 0.f);
    float4* dst = (float4*)(cemb + (size_t)n * 32);
    #pragma unroll
    for (int q = 0; q < 8; q++){
        float4 r;
        #pragma unroll
        for (int j = 0; j < 4; j++) (&r.x)[j] = h[q*4 + j];
        dst[q] = r;
    }
    float p[32];
    #pragma unroll
    for (int o = 0; o < 32; o++) p[o] = 0.f;
    #pragma unroll
    for (int k = 0; k < 32; k++){
        float hk = h[k];
        const float* w = W1c + k*32;
        #pragma unroll
        for (int o = 0; o < 32; o++) p[o] = fmaf(hk, w[o], p[o]);
    }
    f16x8* dp = (f16x8*)(P + (size_t)n * 32);
    #pragma unroll
    for (int q = 0; q < 4; q++){
        f16x8 r;
        #pragma unroll
        for (int j = 0; j < 8; j++) r[j] = (_Float16)p[q*8 + j];
        dp[q] = r;
    }
}

__global__ __launch_bounds__(256) void k_out(
    const float* __restrict__ acc, const float* __restrict__ vemb,
    const float* __restrict__ Wvr, const float* __restrict__ bvr,
    const float* __restrict__ Wo1, const float* __restrict__ bo1,
    const float* __restrict__ Wo2, const float* __restrict__ bo2,
    const float* __restrict__ Wo3, const float* __restrict__ bo3,
    float* __restrict__ out)
{
    int n = blockIdx.x * blockDim.x + threadIdx.x;
    if (n >= NV_N) return;
    float a[32];
    #pragma unroll
    for (int o = 0; o < 32; o++) a[o] = bvr[o];
    const float4* ap = (const float4*)(acc + (size_t)n * 32);
    #pragma unroll
    for (int q = 0; q < 8; q++){
        float4 t = ap[q];
        #pragma unroll
        for (int j = 0; j < 4; j++){
            float xk = (&t.x)[j];
            const float* w = Wvr + (q*4 + j)*32;
            #pragma unroll
            for (int o = 0; o < 32; o++) a[o] = fmaf(xk, w[o], a[o]);
        }
    }
    const float4* vp = (const float4*)(vemb + (size_t)n * 32);
    #pragma unroll
    for (int q = 0; q < 8; q++){
        float4 t = vp[q];
        #pragma unroll
        for (int j = 0; j < 4; j++){
            float xk = (&t.x)[j];
            const float* w = Wvr + (32 + q*4 + j)*32;
            #pragma unroll
            for (int o = 0; o < 32; o++) a[o] = fmaf(xk, w[o], a[o]);
        }
    }
    #pragma unroll
    for (int o = 0; o < 32; o++) a[o] = fmaxf(a[o], 0.f);

    float c[32];
    #pragma unroll
    for (int o = 0; o < 32; o++) c[o] = bo1[o];
    #pragma unroll
    for (int k = 0; k < 32; k++){
        float ak = a[k];
        const float* w = Wo1 + k*32;
        #pragma unroll
        for (int o = 0; o < 32; o++) c[o] = fmaf(ak, w[o], c[o]);
    }
    #pragma unroll
    for (int o = 0; o < 32; o++) c[o] = fmaxf(c[o], 0.f);

    float d[32];
    #pragma unroll
    for (int o = 0; o < 32; o++) d[o] = bo2[o];
    #pragma unroll
    for (int k = 0; k < 32; k++){
        float ck = c[k];
        const float* w = Wo2 + k*32;
        #pragma unroll
        for (int o = 0; o < 32; o++) d[o] = fmaf(ck, w[o], d[o]);
    }
    float s = bo3[0];
    #pragma unroll
    for (int k = 0; k < 32; k++) s = fmaf(fmaxf(d[k], 0.f), Wo3[k], s);
    out[n] = s;
}

// ---------------- launch ----------------

extern "C" void kernel_launch(void* const* d_in, const int* in_sizes, int n_in,
                              void* d_out, int out_size, void* d_ws, size_t ws_size,
                              hipStream_t stream)
{
    (void)in_sizes; (void)n_in; (void)out_size; (void)ws_size;
    const float* consF = (const float*)d_in[0];
    const float* varsF = (const float*)d_in[1];
    const int*   eidx  = (const int*)d_in[2];
    const int*   eCons = eidx;
    const int*   eVars = eidx + E_N;

    const float* Wc  = (const float*)d_in[3],  *bc  = (const float*)d_in[4];
    const float* Wv  = (const float*)d_in[5],  *bv  = (const float*)d_in[6];
    const float* Wj1 = (const float*)d_in[7],  *bj1 = (const float*)d_in[8];
    const float* Wj2 = (const float*)d_in[9],  *bj2 = (const float*)d_in[10];
    const float* Wcr = (const float*)d_in[11], *bcr = (const float*)d_in[12];
    const float* Wvr = (const float*)d_in[13], *bvr = (const float*)d_in[14];
    const float* Wo1 = (const float*)d_in[15], *bo1 = (const float*)d_in[16];
    const float* Wo2 = (const float*)d_in[17], *bo2 = (const float*)d_in[18];
    const float* Wo3 = (const float*)d_in[19], *bo3 = (const float*)d_in[20];

    const size_t NT = (size_t)100000 * 32;
    float*    c_emb = (float*)d_ws;             // 12.8 MB; -> out_c in place
    float*    v_emb = c_emb + NT;               // 12.8 MB
    _Float16* P1    = (_Float16*)(v_emb + NT);  // 6.4 MB fp16 (var pass1 / const pass2)
    _Float16* P2    = P1 + NT;                  // 6.4 MB fp16 (const pass1 / var pass2)
    float*    accum = (float*)(P2 + NT);        // 12.8 MB segment sums
    unsigned* pbuf  = (unsigned*)P1;            // overlay 25.6MB+PAD over P1..accum+PAD
    int*   cnt     = (int*)(accum + NT) + PAD;  // [NKEY]  (PAD ints reserved for pbuf tail)
    int*   offs    = cnt + NKEY;                // [NKEY]
    int*   hists   = offs + NKEY;               // [NSB*NBLK_A]
    int*   partial = hists + NSB*NBLK_A;        // [NSB*NBLK_A]
    int*   total   = partial + NSB*NBLK_A;      // [NSB]
    int*   bbase   = total + NSB;               // [NSB]
    int*   elist   = bbase + NSB;               // [2E + PAD]
    _Float16* w2hi = (_Float16*)(elist + 2*E_N + PAD);  // [2][64][8]
    _Float16* w2lo = w2hi + 1024;

    const float* W1c = Wj1;                     // rows 0..31  (cons/out_c side)
    const float* W1v = Wj1 + 32*32;             // rows 32..63 (vars side)

    // --- deterministic 3-phase counting sort for BOTH directions ---
    k_sbhist<<<dim3(NBLK_A), dim3(256), 0, stream>>>(eCons, eVars, hists);
    k_scanA<<<dim3(NSB), dim3(512), 0, stream>>>(hists, partial, total);
    k_scanB_w2<<<dim3(1), dim3(512), 0, stream>>>(total, bbase, Wj2, w2hi, w2lo);
    k_sbscatter<<<dim3(NBLK_A), dim3(256), 0, stream>>>(eCons, eVars, partial, bbase, pbuf);
    k_sbsort<<<dim3(NSB), dim3(256), 0, stream>>>(pbuf, bbase, total, cnt, offs, elist);

    // --- fused embeddings + layer-1 hoist (P1/P2 overwrite: pbuf is dead now) ---
    k_embed_all<<<dim3(782), dim3(256), 0, stream>>>(consF, varsF, Wc, bc, Wv, bv,
                                                     W1c, W1v, c_emb, v_emb, P2, P1);

    // ---- pass 1: edges -> constraints (keys [0,NC)) ----
    k_edge_mfma<<<dim3(25000), dim3(256), 0, stream>>>(
        P2, P1, offs, cnt, elist, w2hi, w2lo, bj1, bj2, accum, NC_N);
    k_consrep_f<<<dim3(391), dim3(256), 0, stream>>>(accum, c_emb, Wcr, bcr, W1c, P2);

    // ---- pass 2: edges -> variables (keys [NC,NC+NV)) ----
    k_edge_mfma<<<dim3(25000), dim3(256), 0, stream>>>(
        P1, P2, offs + NC_N, cnt + NC_N, elist, w2hi, w2lo, bj1, bj2, accum, NV_N);
    k_out<<<dim3(391), dim3(256), 0, stream>>>(accum, v_emb, Wvr, bvr,
                                               Wo1, bo1, Wo2, bo2, Wo3, bo3,
                                               (float*)d_out);
}